// Round 14
// baseline (623.041 us; speedup 1.0000x reference)
//
#include <hip/hip_runtime.h>

#define BLOCK 256
#define NNODE 1024
#define NH    992
#define NE    1984
#define NSORT 2048
#define LMAX  12
#define CHUNK 64
#define NPASS (NE / CHUNK)

typedef unsigned long long ull;

__device__ __forceinline__ void edge_nodes(int e, int& a, int& b) {
    if (e < NH) {                 // horizontal: (r,c)-(r,c+1), e = r*31+c
        int r = e / 31;
        int c = e - r * 31;
        a = (r << 5) + c;
        b = a + 1;
    } else {                      // vertical: (r,c)-(r+1,c), e-992 = r*32+c
        a = e - NH;
        b = a + 32;
    }
}

__device__ __forceinline__ int find_par(unsigned short* par, int x) {
    volatile unsigned short* vp = par;
    int r = x;
    int p = vp[r];
    while (p != r) { r = p; p = vp[r]; }
    int c = x;
    while (c != r) { const int nxt = vp[c]; vp[c] = (unsigned short)r; c = nxt; }
    return r;
}

__device__ __forceinline__ int dot16x4(ull a, ull b) {
    int s  = (int)(a & 0xFFFFu)         * (int)(b & 0xFFFFu);
    s     += (int)((a >> 16) & 0xFFFFu) * (int)((b >> 16) & 0xFFFFu);
    s     += (int)((a >> 32) & 0xFFFFu) * (int)((b >> 32) & 0xFFFFu);
    s     += (int)((a >> 48) & 0xFFFFu) * (int)((b >> 48) & 0xFFFFu);
    return s;
}

__device__ __forceinline__ void cswap(unsigned int& ka, unsigned short& ia,
                                      unsigned int& kb, unsigned short& ib, bool up) {
    const bool gt = (ka > kb) || (ka == kb && ia > ib);
    if (gt == up) {
        const unsigned int  tk = ka; ka = kb; kb = tk;
        const unsigned short ti = ia; ia = ib; ib = ti;
    }
}

// ----------------------------------------------------------------------------
// Hybrid Kruskal (wave 0) — r13 structure; serial-tail broadcast switched from
// __shfl (ds_bpermute, ~LDS latency) to __builtin_amdgcn_readlane (v_readlane,
// VALU latency) — valid because the source lane i = ctz(ballot) is
// wave-uniform. This removes one of the two ~120-cycle latency events from
// every serial iteration.
// Per 64-edge pass (MODE<=1):
//  (a) ONE claim round: candidate lanes atomicMax both roots with tag
//      ((pass+1)<<6)|(63-lane): max tag == MIN lane; tags monotone over passes
//      so stale tags always lose -> no reset needed.
//  (b) winners (own both claims) == greedy prefix-independent set -> commit
//      IN PARALLEL per-lane (mutually disjoint; exact serial-prefix state).
//  (c) losers re-find and run the serial loop (readlane pack, wave-uniform
//      state loads, register-maintained roots).
// Claims alias unused sh_cnt64 words: MODE 0 -> u32[node]; MODE 1 -> u32 at
// node*6+2 (low half of unused word-1). MODE 2 (L>=5, rare) is pure serial.
// ----------------------------------------------------------------------------
template<int MODE>
__device__ __forceinline__ void kruskal_run(unsigned short* sh_parent,
                                            unsigned int*   sh_szto,
                                            ull*            sh_cnt64,
                                            unsigned int*   sh_key,
                                            const unsigned short* sh_idx,
                                            const int sign, const int lane) {
    unsigned int* claim32 = (unsigned int*)sh_cnt64;
    for (int pass = 0; pass < NPASS; ++pass) {
        const int e = sh_idx[pass * CHUNK + lane];
        int a, bb; edge_nodes(e, a, bb);
        int ra = find_par(sh_parent, a);
        int rb = find_par(sh_parent, bb);
        bool cand = (ra != rb);

        if (MODE <= 1) {
            const unsigned int tag = ((unsigned int)(pass + 1) << 6) | (unsigned int)(63 - lane);
            const int ia = (MODE == 0) ? ra : (ra * 6 + 2);
            const int ib = (MODE == 0) ? rb : (rb * 6 + 2);
            if (cand) {
                atomicMax(&claim32[ia], tag);
                atomicMax(&claim32[ib], tag);
            }
            asm volatile("s_waitcnt lgkmcnt(0)" ::: "memory");
            __builtin_amdgcn_sched_barrier(0);
            bool win = false;
            if (cand) win = (claim32[ia] == tag) && (claim32[ib] == tag);
            if (win) {
                // parallel commit: winners' root pairs are mutually disjoint
                const unsigned int xa = sh_szto[ra], xb = sh_szto[rb];
                const int ta = (int)(xa >> 16), tb = (int)(xb >> 16);
                int wv;
                ull a0 = 0, b0 = 0;
                if (MODE == 0) {
                    wv = ta * tb;                 // L==1: same == ta*tb
                } else {
                    a0 = sh_cnt64[ra * 3]; b0 = sh_cnt64[rb * 3];
                    const int same = dot16x4(a0, b0);
                    wv = sign ? same : (ta * tb - same);
                }
                const int big = ((xa & 0xFFFFu) > (xb & 0xFFFFu));
                const int rs = big ? ra : rb;     // survivor (union by size)
                const int rl = big ? rb : ra;
                sh_key[e] = __float_as_uint((float)wv);
                sh_szto[rs] = xa + xb;            // sums <= 2048: no field carry
                if (MODE == 1) sh_cnt64[rs * 3] = a0 + b0;  // per-lane sums <= 1024
                sh_parent[rl] = (unsigned short)rs;
                cand = false;                     // handled
            }
            asm volatile("s_waitcnt lgkmcnt(0)" ::: "memory");
            __builtin_amdgcn_sched_barrier(0);
            if (cand) {                           // tail: re-find post-winners
                ra = find_par(sh_parent, ra);
                rb = find_par(sh_parent, rb);
                cand = (ra != rb);
            }
        }

        // ---- serial tail (readlane pack, wave-uniform state loads) ----
        const unsigned int pack = (unsigned int)ra | ((unsigned int)rb << 10) | ((unsigned int)e << 20);
        ull m = __ballot(cand);
        int rl_prev = -1, rs_prev = -1;           // register-tracked remaps
        while (m) {
            const int i = (int)__builtin_ctzll(m);
            m &= m - 1;
            // wave-uniform lane index -> v_readlane (VALU), not ds_bpermute
            unsigned int pk = (unsigned int)__builtin_amdgcn_readlane((int)pack, i);
            int ra_i = (int)(pk & 1023u);
            int rb_i = (int)((pk >> 10) & 1023u);
            // apply register-tracked remaps from all prior commits this pass:
            // each lane's own (ra, rb) registers are updated below; the pack we
            // just read is the ORIGINAL snapshot, so re-find via parent array
            // (usually 0-1 hops since winners/commits wrote parents).
            {
                int p1 = sh_parent[ra_i];
                while (p1 != ra_i) { ra_i = p1; p1 = sh_parent[ra_i]; }
                int p2 = sh_parent[rb_i];
                while (p2 != rb_i) { rb_i = p2; p2 = sh_parent[rb_i]; }
            }
            if (ra_i == rb_i) continue;           // became a cycle mid-pass
            const int se = (int)(pk >> 20);
            const unsigned int xa = sh_szto[ra_i], xb = sh_szto[rb_i];
            const int ta = (int)(xa >> 16), tb = (int)(xb >> 16);
            const int big = ((xa & 0xFFFFu) > (xb & 0xFFFFu));
            const int rs = big ? ra_i : rb_i;
            const int rl = big ? rb_i : ra_i;
            int wv;
            if (MODE == 0) {
                wv = ta * tb;
            } else if (MODE == 1) {
                const ull a0 = sh_cnt64[ra_i * 3];
                const ull b0 = sh_cnt64[rb_i * 3];
                const int same = dot16x4(a0, b0);
                wv = sign ? same : (ta * tb - same);
                if (lane == 0 && (ta + tb) > 0)
                    sh_cnt64[rs * 3] = a0 + b0;
            } else {
                const ull a0 = sh_cnt64[ra_i * 3 + 0];
                const ull a1 = sh_cnt64[ra_i * 3 + 1];
                const ull a2 = sh_cnt64[ra_i * 3 + 2];
                const ull b0 = sh_cnt64[rb_i * 3 + 0];
                const ull b1 = sh_cnt64[rb_i * 3 + 1];
                const ull b2 = sh_cnt64[rb_i * 3 + 2];
                const int same = dot16x4(a0, b0) + dot16x4(a1, b1) + dot16x4(a2, b2);
                wv = sign ? same : (ta * tb - same);
                if (lane == 0 && (ta + tb) > 0) {
                    sh_cnt64[rs * 3 + 0] = a0 + b0;
                    sh_cnt64[rs * 3 + 1] = a1 + b1;
                    sh_cnt64[rs * 3 + 2] = a2 + b2;
                }
            }
            if (lane == 0) {
                sh_key[se] = __float_as_uint((float)wv);
                sh_szto[rs] = xa + xb;
                sh_parent[rl] = (unsigned short)rs;
            }
            (void)rl_prev; (void)rs_prev;
        }
    }
}

// shared UF init (claims zeroed in the aliased words)
template<int MODE>
__device__ __forceinline__ void uf_init(unsigned short* sh_parent,
                                        unsigned int* sh_szto,
                                        ull* sh_cnt64,
                                        const unsigned char* sh_seg,
                                        const int tid) {
    unsigned int* claim32 = (unsigned int*)sh_cnt64;
    for (int pix = tid; pix < NNODE; pix += BLOCK) {
        sh_parent[pix] = (unsigned short)pix;
        const int s = sh_seg[pix];
        const unsigned int tot = (s > 0 && s <= LMAX) ? 1u : 0u;
        sh_szto[pix] = 1u | (tot << 16);
        if (MODE == 0) {
            claim32[pix] = 0u;                    // claim array
        } else {
            ull c0 = 0, c1 = 0, c2 = 0;
            if (s >= 1 && s <= LMAX) {
                const ull bit = 1ull << (((s - 1) & 3) * 16);
                const int q = (s - 1) >> 2;
                if (q == 0) c0 = bit; else if (q == 1) c1 = bit; else c2 = bit;
            }
            sh_cnt64[pix * 3 + 0] = c0;
            sh_cnt64[pix * 3 + 1] = (MODE == 1) ? 0ull : c1;   // mode1: claim word
            if (MODE == 2) sh_cnt64[pix * 3 + 2] = c2;
        }
    }
}

// ============================================================================
// prep_kernel: one block per (item, win, b). Projection + dilate + CC + label.
// axis_id==2 blocks additionally accumulate the MSE (each voxel exactly once).
// ============================================================================
__global__ __launch_bounds__(BLOCK) void prep_kernel(const float* __restrict__ pred,
                                                     const float* __restrict__ tgt,
                                                     char* __restrict__ ws,
                                                     double* __restrict__ acc_ws,
                                                     int B) {
    __shared__ alignas(16) float sh_p[NNODE];
    __shared__ alignas(16) float sh_t[NNODE];
    __shared__ unsigned char  mA[NNODE];
    __shared__ unsigned char  mB[NNODE];
    __shared__ unsigned short sh_parent[NNODE];
    __shared__ unsigned short sh_lab[NNODE];
    __shared__ int sh_L;
    __shared__ double sh_redp[4];

    const int tid = threadIdx.x;
    const int w = blockIdx.x;                         // work index
    int wg = w;
    const int b    = wg % B;  wg /= B;
    const int win  = wg & 3;  wg >>= 2;
    const int item = wg;                              // 0..23
    const int axis_id = item % 3;
    const int cube = item / 3;
    const int ci = cube & 1;
    const int cj = (cube >> 1) & 1;
    const int ck = (cube >> 2) & 1;
    const int wk = win >> 1;
    const int wj = win & 1;

    const int NW = 96 * B;
    float* Pb = (float*)(ws + 64);
    float* Tb = Pb + (size_t)NW * NNODE;
    unsigned char* Sb = (unsigned char*)(Tb + (size_t)NW * NNODE);
    int* Lb = (int*)(Sb + (size_t)NW * NNODE);

    const size_t base = (size_t)b * 2097152u;

    // ---- projection mins (32x32 window of the 64x64 projection) ----
    if (axis_id == 2) {
        // contiguous along the reduced axis: float4 loads; also accumulate MSE
        double msum = 0.0;
        for (int pix = tid; pix < NNODE; pix += BLOCK) {
            const int r = pix >> 5, c = pix & 31;
            const int R = wk * 32 + r, C = wj * 32 + c;
            const size_t idx0 = base + (size_t)(ck * 64 + R) * 16384u + (size_t)(cj * 64 + C) * 128u + (size_t)(ci * 64);
            const float4* pp = reinterpret_cast<const float4*>(pred + idx0);
            const float4* tp = reinterpret_cast<const float4*>(tgt + idx0);
            float pm = 3.4e38f, tm = 3.4e38f;
            #pragma unroll
            for (int h = 0; h < 16; ++h) {
                const float4 a = pp[h];
                const float4 t = tp[h];
                pm = fminf(pm, fminf(fminf(a.x, a.y), fminf(a.z, a.w)));
                tm = fminf(tm, fminf(fminf(t.x, t.y), fminf(t.z, t.w)));
                const float dx = a.x - t.x, dy = a.y - t.y;
                const float dz = a.z - t.z, dw = a.w - t.w;
                msum += (double)(dx * dx);
                msum += (double)(dy * dy);
                msum += (double)(dz * dz);
                msum += (double)(dw * dw);
            }
            sh_p[pix] = pm;
            sh_t[pix] = tm;
        }
        for (int off = 32; off > 0; off >>= 1) msum += __shfl_down(msum, off, 64);
        if ((tid & 63) == 0) sh_redp[tid >> 6] = msum;
        __syncthreads();
        if (tid == 0)
            atomicAdd(&acc_ws[0], sh_redp[0] + sh_redp[1] + sh_redp[2] + sh_redp[3]);
    } else {
        const int r  = tid >> 3;
        const int c0 = (tid & 7) << 2;
        const int R = wk * 32 + r, C = wj * 32 + c0;
        size_t idx0; int hstride;
        if (axis_id == 0) {
            idx0 = base + (size_t)(ck * 64) * 16384u + (size_t)(cj * 64 + R) * 128u + (size_t)(ci * 64 + C);
            hstride = 16384;
        } else {
            idx0 = base + (size_t)(ck * 64 + R) * 16384u + (size_t)(cj * 64) * 128u + (size_t)(ci * 64 + C);
            hstride = 128;
        }
        float4 pm = make_float4(3.4e38f, 3.4e38f, 3.4e38f, 3.4e38f);
        float4 tm = pm;
        #pragma unroll 8
        for (int h = 0; h < 64; ++h) {
            const float4 a  = *reinterpret_cast<const float4*>(pred + idx0);
            const float4 t4 = *reinterpret_cast<const float4*>(tgt + idx0);
            pm.x = fminf(pm.x, a.x);  pm.y = fminf(pm.y, a.y);
            pm.z = fminf(pm.z, a.z);  pm.w = fminf(pm.w, a.w);
            tm.x = fminf(tm.x, t4.x); tm.y = fminf(tm.y, t4.y);
            tm.z = fminf(tm.z, t4.z); tm.w = fminf(tm.w, t4.w);
            idx0 += (size_t)hstride;
        }
        *reinterpret_cast<float4*>(&sh_p[(r << 5) + c0]) = pm;
        *reinterpret_cast<float4*>(&sh_t[(r << 5) + c0]) = tm;
        __syncthreads();
    }

    // ---- dilate5 of (t == 0), von Neumann, zero padded, window-local ----
    for (int pix = tid; pix < NNODE; pix += BLOCK)
        mA[pix] = (sh_t[pix] == 0.0f) ? 1 : 0;
    __syncthreads();
    for (int it = 0; it < 5; ++it) {
        unsigned char* src = (it & 1) ? mB : mA;
        unsigned char* dst = (it & 1) ? mA : mB;
        for (int pix = tid; pix < NNODE; pix += BLOCK) {
            const int r = pix >> 5, c = pix & 31;
            unsigned char v = src[pix];
            if (r > 0)  v |= src[pix - 32];
            if (r < 31) v |= src[pix + 32];
            if (c > 0)  v |= src[pix - 1];
            if (c < 31) v |= src[pix + 1];
            dst[pix] = v;
        }
        __syncthreads();
    }
    for (int pix = tid; pix < NNODE; pix += BLOCK)
        mA[pix] = mB[pix] ^ 1;                        // fg
    __syncthreads();

    // ---- 8-connected CC labeling on fg via min-index propagation ----
    for (int pix = tid; pix < NNODE; pix += BLOCK)
        sh_parent[pix] = mA[pix] ? (unsigned short)pix : (unsigned short)0xFFFF;
    __syncthreads();
    for (;;) {
        int changed = 0;
        for (int pix = tid; pix < NNODE; pix += BLOCK) {
            if (!mA[pix]) continue;
            const int r = pix >> 5, c = pix & 31;
            int m = sh_parent[pix];
            #pragma unroll
            for (int d = 0; d < 8; ++d) {
                static const int dr[8] = {-1,-1,-1, 0, 0, 1, 1, 1};
                static const int dc[8] = {-1, 0, 1,-1, 1,-1, 0, 1};
                const int rr = r + dr[d], cc = c + dc[d];
                if (rr < 0 || rr > 31 || cc < 0 || cc > 31) continue;
                const int nb = (rr << 5) + cc;
                if (mA[nb]) { int v = sh_parent[nb]; if (v < m) m = v; }
            }
            while ((int)sh_parent[m] < m) m = sh_parent[m];
            if (m < (int)sh_parent[pix]) { sh_parent[pix] = (unsigned short)m; changed = 1; }
        }
        if (!__syncthreads_or(changed)) break;
    }

    // ---- compact labels ----
    if (tid == 0) sh_L = 0;
    __syncthreads();
    for (int pix = tid; pix < NNODE; pix += BLOCK) {
        if (mA[pix] && (int)sh_parent[pix] == pix) {
            const int id = atomicAdd(&sh_L, 1);
            sh_lab[pix] = (unsigned short)(id + 1);
        }
    }
    __syncthreads();

    // ---- write P, T, SEG, L to workspace (coalesced) ----
    {
        const int p4 = tid << 2;                      // exactly one float4 per thread
        *reinterpret_cast<float4*>(&Pb[(size_t)w * NNODE + p4]) =
            *reinterpret_cast<const float4*>(&sh_p[p4]);
        *reinterpret_cast<float4*>(&Tb[(size_t)w * NNODE + p4]) =
            *reinterpret_cast<const float4*>(&sh_t[p4]);
        unsigned int packed = 0;
        #pragma unroll
        for (int q = 0; q < 4; ++q) {
            const int pix = p4 + q;
            unsigned int s = 0;
            if (mA[pix]) {
                int lab = sh_lab[sh_parent[pix]];
                if (lab > 255) lab = 255;
                s = (unsigned int)lab;
            }
            packed |= s << (q * 8);
        }
        ((unsigned int*)Sb)[(size_t)w * (NNODE / 4) + tid] = packed;
        if (tid == 0) Lb[w] = sh_L;
    }
}

// ============================================================================
// solve_kernel: one block per (sign, item, win, b). Reads P/T/SEG/L; skips
// exact-zero blocks instantly; key-build + sort + hybrid Kruskal + gather.
// ============================================================================
__global__ __launch_bounds__(BLOCK) void solve_kernel(const char* __restrict__ ws_c,
                                                      double* __restrict__ acc_ws,
                                                      int B) {
    __shared__ alignas(16) float          sh_p[NNODE];
    __shared__ alignas(16) float          sh_t[NNODE];
    __shared__ alignas(16) unsigned int   sh_key[NSORT];
    __shared__ alignas(16) unsigned short sh_idx[NSORT];
    __shared__ unsigned short sh_parent[NNODE];
    __shared__ unsigned int   sh_szto[NNODE];
    __shared__ ull            sh_cnt64[NNODE * 3];
    __shared__ alignas(16) unsigned char sh_seg[NNODE];
    __shared__ float          sh_sn;
    __shared__ double         sh_red[4];

    const int tid = threadIdx.x;
    int wg = blockIdx.x;
    const int sign = wg & 1;  wg >>= 1;
    const int w = wg;                                  // work index 0..96B-1

    const int NW = 96 * B;
    const float* Pb = (const float*)(ws_c + 64);
    const float* Tb = Pb + (size_t)NW * NNODE;
    const unsigned char* Sb = (const unsigned char*)(Tb + (size_t)NW * NNODE);
    const int* Lb = (const int*)(Sb + (size_t)NW * NNODE);

    // ---- skip check before touching LDS ----
    const int Lraw = Lb[w];
    if (Lraw == 0 || (Lraw == 1 && sign == 0)) return;   // exact-zero contribution
    const int mode = (Lraw <= 1) ? 0 : ((Lraw <= 4) ? 1 : 2);

    // ---- load P/T/SEG (one float4 / u32 per thread) ----
    {
        const int p4 = tid << 2;
        *reinterpret_cast<float4*>(&sh_p[p4]) =
            *reinterpret_cast<const float4*>(&Pb[(size_t)w * NNODE + p4]);
        *reinterpret_cast<float4*>(&sh_t[p4]) =
            *reinterpret_cast<const float4*>(&Tb[(size_t)w * NNODE + p4]);
        ((unsigned int*)sh_seg)[tid] =
            ((const unsigned int*)Sb)[(size_t)w * (NNODE / 4) + tid];
    }
    __syncthreads();

    // ---- union-find init (incl. claim zeroing) ----
    if (mode == 0)      uf_init<0>(sh_parent, sh_szto, sh_cnt64, sh_seg, tid);
    else if (mode == 1) uf_init<1>(sh_parent, sh_szto, sh_cnt64, sh_seg, tid);
    else                uf_init<2>(sh_parent, sh_szto, sh_cnt64, sh_seg, tid);
    __syncthreads();

    // ---- build sort keys in registers + k=2,4,8 rounds before first store ----
    unsigned int   K[8];
    unsigned short I[8];
    const int b8 = tid << 3;
    #pragma unroll
    for (int l = 0; l < 8; ++l) {
        const int e = b8 + l;
        if (e < NE) {
            int a, bb; edge_nodes(e, a, bb);
            float cost = sh_p[a] + sh_p[bb];
            const float g = sh_t[a] + sh_t[bb];
            if (sign == 0) { if (g > 10.0f) cost = 10.0f; }
            else           { if (g <  3.0f) cost = 0.0f;  }
            K[l] = ~__float_as_uint(cost);
            I[l] = (unsigned short)e;
        } else {
            K[l] = 0xFFFFFFFFu;
            I[l] = (unsigned short)0xFFFF;
        }
    }
    cswap(K[0],I[0],K[1],I[1], true );
    cswap(K[2],I[2],K[3],I[3], false);
    cswap(K[4],I[4],K[5],I[5], true );
    cswap(K[6],I[6],K[7],I[7], false);
    cswap(K[0],I[0],K[2],I[2], true );
    cswap(K[1],I[1],K[3],I[3], true );
    cswap(K[4],I[4],K[6],I[6], false);
    cswap(K[5],I[5],K[7],I[7], false);
    cswap(K[0],I[0],K[1],I[1], true );
    cswap(K[2],I[2],K[3],I[3], true );
    cswap(K[4],I[4],K[5],I[5], false);
    cswap(K[6],I[6],K[7],I[7], false);
    {
        const bool u8 = ((b8 & 8) == 0);
        cswap(K[0],I[0],K[4],I[4], u8); cswap(K[1],I[1],K[5],I[5], u8);
        cswap(K[2],I[2],K[6],I[6], u8); cswap(K[3],I[3],K[7],I[7], u8);
        cswap(K[0],I[0],K[2],I[2], u8); cswap(K[1],I[1],K[3],I[3], u8);
        cswap(K[4],I[4],K[6],I[6], u8); cswap(K[5],I[5],K[7],I[7], u8);
        cswap(K[0],I[0],K[1],I[1], u8); cswap(K[2],I[2],K[3],I[3], u8);
        cswap(K[4],I[4],K[5],I[5], u8); cswap(K[6],I[6],K[7],I[7], u8);
    }
    {
        uint4 k0, k1, iv;
        k0.x=K[0]; k0.y=K[1]; k0.z=K[2]; k0.w=K[3];
        k1.x=K[4]; k1.y=K[5]; k1.z=K[6]; k1.w=K[7];
        iv.x=(unsigned int)I[0] | ((unsigned int)I[1]<<16);
        iv.y=(unsigned int)I[2] | ((unsigned int)I[3]<<16);
        iv.z=(unsigned int)I[4] | ((unsigned int)I[5]<<16);
        iv.w=(unsigned int)I[6] | ((unsigned int)I[7]<<16);
        *reinterpret_cast<uint4*>(&sh_key[b8])     = k0;
        *reinterpret_cast<uint4*>(&sh_key[b8 + 4]) = k1;
        *reinterpret_cast<uint4*>(&sh_idx[b8])     = iv;
    }
    __syncthreads();

    // ---- bitonic k=16..2048: j>=8 via LDS pair-indexed, j=4,2,1 in registers ----
    for (int k = 16; k <= NSORT; k <<= 1) {
        for (int j = k >> 1; j >= 8; j >>= 1) {
            for (int p = tid; p < (NSORT >> 1); p += BLOCK) {
                const int i   = ((p & ~(j - 1)) << 1) | (p & (j - 1));
                const int ixj = i | j;
                const unsigned int ka = sh_key[i], kb = sh_key[ixj];
                const unsigned short ia = sh_idx[i], ib = sh_idx[ixj];
                const bool gt = (ka > kb) || (ka == kb && ia > ib);
                const bool up = ((i & k) == 0);
                if (gt == up) {
                    sh_key[i] = kb; sh_key[ixj] = ka;
                    sh_idx[i] = ib; sh_idx[ixj] = ia;
                }
            }
            __syncthreads();
        }
        {
            const uint4 k0 = *reinterpret_cast<const uint4*>(&sh_key[b8]);
            const uint4 k1 = *reinterpret_cast<const uint4*>(&sh_key[b8 + 4]);
            const uint4 iv = *reinterpret_cast<const uint4*>(&sh_idx[b8]);
            K[0]=k0.x; K[1]=k0.y; K[2]=k0.z; K[3]=k0.w;
            K[4]=k1.x; K[5]=k1.y; K[6]=k1.z; K[7]=k1.w;
            I[0]=(unsigned short)(iv.x); I[1]=(unsigned short)(iv.x>>16);
            I[2]=(unsigned short)(iv.y); I[3]=(unsigned short)(iv.y>>16);
            I[4]=(unsigned short)(iv.z); I[5]=(unsigned short)(iv.z>>16);
            I[6]=(unsigned short)(iv.w); I[7]=(unsigned short)(iv.w>>16);
            const bool u8 = ((b8 & k) == 0);
            cswap(K[0],I[0],K[4],I[4], u8); cswap(K[1],I[1],K[5],I[5], u8);
            cswap(K[2],I[2],K[6],I[6], u8); cswap(K[3],I[3],K[7],I[7], u8);
            cswap(K[0],I[0],K[2],I[2], u8); cswap(K[1],I[1],K[3],I[3], u8);
            cswap(K[4],I[4],K[6],I[6], u8); cswap(K[5],I[5],K[7],I[7], u8);
            cswap(K[0],I[0],K[1],I[1], u8); cswap(K[2],I[2],K[3],I[3], u8);
            cswap(K[4],I[4],K[5],I[5], u8); cswap(K[6],I[6],K[7],I[7], u8);
            uint4 o0, o1, ov;
            o0.x=K[0]; o0.y=K[1]; o0.z=K[2]; o0.w=K[3];
            o1.x=K[4]; o1.y=K[5]; o1.z=K[6]; o1.w=K[7];
            ov.x=(unsigned int)I[0] | ((unsigned int)I[1]<<16);
            ov.y=(unsigned int)I[2] | ((unsigned int)I[3]<<16);
            ov.z=(unsigned int)I[4] | ((unsigned int)I[5]<<16);
            ov.w=(unsigned int)I[6] | ((unsigned int)I[7]<<16);
            *reinterpret_cast<uint4*>(&sh_key[b8])     = o0;
            *reinterpret_cast<uint4*>(&sh_key[b8 + 4]) = o1;
            *reinterpret_cast<uint4*>(&sh_idx[b8])     = ov;
        }
        __syncthreads();
    }

    // ---- zero edge weights ----
    for (int e = tid; e < NE; e += BLOCK) sh_key[e] = 0u;
    __syncthreads();

    // ---- single-wave hybrid Kruskal (wave 0) ----
    if (tid < 64) {
        if (mode == 0)      kruskal_run<0>(sh_parent, sh_szto, sh_cnt64, sh_key, sh_idx, sign, tid);
        else if (mode == 1) kruskal_run<1>(sh_parent, sh_szto, sh_cnt64, sh_key, sh_idx, sign, tid);
        else                kruskal_run<2>(sh_parent, sh_szto, sh_cnt64, sh_key, sh_idx, sign, tid);
    }
    __syncthreads();

    // ---- normalization sum ----
    {
        float part = 0.0f;
        for (int e = tid; e < NE; e += BLOCK) part += __uint_as_float(sh_key[e]);
        for (int off = 32; off > 0; off >>= 1) part += __shfl_down(part, off, 64);
        if ((tid & 63) == 0) sh_red[tid >> 6] = (double)part;
        __syncthreads();
        if (tid == 0) sh_sn = (float)(sh_red[0] + sh_red[1] + sh_red[2] + sh_red[3]);
        __syncthreads();
    }
    const float sn = sh_sn;

    // ---- per-node gather + conn contribution ----
    double acc = 0.0;
    for (int pix = tid; pix < NNODE; pix += BLOCK) {
        const int r = pix >> 5, c = pix & 31;
        float nw = 0.0f;
        if (c < 31) { const int e = r * 31 + c;
            float v = __uint_as_float(sh_key[e]); if (sn > 0.0f) v = v / sn;
            const float g = sh_t[pix] + sh_t[pix + 1];
            if (sign == 0) { if (g >= 3.0f) v = 0.0f; } else { if (g < 10.0f) v = 0.0f; }
            nw += v; }
        if (c > 0)  { const int e = r * 31 + c - 1;
            float v = __uint_as_float(sh_key[e]); if (sn > 0.0f) v = v / sn;
            const float g = sh_t[pix - 1] + sh_t[pix];
            if (sign == 0) { if (g >= 3.0f) v = 0.0f; } else { if (g < 10.0f) v = 0.0f; }
            nw += v; }
        if (r < 31) { const int e = NH + pix;
            float v = __uint_as_float(sh_key[e]); if (sn > 0.0f) v = v / sn;
            const float g = sh_t[pix] + sh_t[pix + 32];
            if (sign == 0) { if (g >= 3.0f) v = 0.0f; } else { if (g < 10.0f) v = 0.0f; }
            nw += v; }
        if (r > 0)  { const int e = NH + pix - 32;
            float v = __uint_as_float(sh_key[e]); if (sn > 0.0f) v = v / sn;
            const float g = sh_t[pix - 32] + sh_t[pix];
            if (sign == 0) { if (g >= 3.0f) v = 0.0f; } else { if (g < 10.0f) v = 0.0f; }
            nw += v; }
        const float p = sh_p[pix];
        float term;
        if (sign == 0) term = (p * p) * nw;
        else { const float d = 20.0f - p; term = (0.1f * (d * d)) * nw; }
        acc += (double)term;
    }
    for (int off = 32; off > 0; off >>= 1) acc += __shfl_down(acc, off, 64);
    if ((tid & 63) == 0) sh_red[tid >> 6] = acc;
    __syncthreads();
    if (tid == 0)
        atomicAdd(&acc_ws[1], sh_red[0] + sh_red[1] + sh_red[2] + sh_red[3]);
}

// ============================================================================
// Fallback fused kernel — used only if the workspace is too small.
// ============================================================================
__global__ __launch_bounds__(BLOCK) void conn_kernel(const float* __restrict__ pred,
                                                     const float* __restrict__ tgt,
                                                     double* __restrict__ acc_ws,
                                                     int B) {
    __shared__ alignas(16) float          sh_p[NNODE];
    __shared__ alignas(16) float          sh_t[NNODE];
    __shared__ alignas(16) unsigned int   sh_key[NSORT];
    __shared__ alignas(16) unsigned short sh_idx[NSORT];
    __shared__ unsigned short sh_parent[NNODE];
    __shared__ unsigned int   sh_szto[NNODE];
    __shared__ ull            sh_cnt64[NNODE * 3];
    __shared__ unsigned char  sh_seg[NNODE];
    __shared__ int            sh_L;
    __shared__ float          sh_sn;
    __shared__ double         sh_red[4];

    const int tid = threadIdx.x;
    int wg = blockIdx.x;
    const int sign = (wg >> 3) & 1;
    wg = (wg & 7) | ((wg >> 4) << 3);
    const int b    = wg % B;  wg /= B;
    const int win  = wg & 3;  wg >>= 2;
    const int item = wg;
    const int axis_id = item % 3;
    const int cube = item / 3;
    const int ci = cube & 1;
    const int cj = (cube >> 1) & 1;
    const int ck = (cube >> 2) & 1;
    const int wk = win >> 1;
    const int wj = win & 1;

    const size_t base = (size_t)b * 2097152u;

    if (axis_id == 2) {
        for (int pix = tid; pix < NNODE; pix += BLOCK) {
            const int r = pix >> 5, c = pix & 31;
            const int R = wk * 32 + r, C = wj * 32 + c;
            const size_t idx0 = base + (size_t)(ck * 64 + R) * 16384u + (size_t)(cj * 64 + C) * 128u + (size_t)(ci * 64);
            const float4* pp = reinterpret_cast<const float4*>(pred + idx0);
            const float4* tp = reinterpret_cast<const float4*>(tgt + idx0);
            float pm = 3.4e38f, tm = 3.4e38f;
            #pragma unroll
            for (int h = 0; h < 16; ++h) {
                const float4 a = pp[h];
                const float4 t = tp[h];
                pm = fminf(pm, fminf(fminf(a.x, a.y), fminf(a.z, a.w)));
                tm = fminf(tm, fminf(fminf(t.x, t.y), fminf(t.z, t.w)));
            }
            sh_p[pix] = pm;
            sh_t[pix] = tm;
        }
    } else {
        const int r  = tid >> 3;
        const int c0 = (tid & 7) << 2;
        const int R = wk * 32 + r, C = wj * 32 + c0;
        size_t idx0; int hstride;
        if (axis_id == 0) {
            idx0 = base + (size_t)(ck * 64) * 16384u + (size_t)(cj * 64 + R) * 128u + (size_t)(ci * 64 + C);
            hstride = 16384;
        } else {
            idx0 = base + (size_t)(ck * 64 + R) * 16384u + (size_t)(cj * 64) * 128u + (size_t)(ci * 64 + C);
            hstride = 128;
        }
        float4 pm = make_float4(3.4e38f, 3.4e38f, 3.4e38f, 3.4e38f);
        float4 tm = pm;
        #pragma unroll 8
        for (int h = 0; h < 64; ++h) {
            const float4 a  = *reinterpret_cast<const float4*>(pred + idx0);
            const float4 t4 = *reinterpret_cast<const float4*>(tgt + idx0);
            pm.x = fminf(pm.x, a.x);  pm.y = fminf(pm.y, a.y);
            pm.z = fminf(pm.z, a.z);  pm.w = fminf(pm.w, a.w);
            tm.x = fminf(tm.x, t4.x); tm.y = fminf(tm.y, t4.y);
            tm.z = fminf(tm.z, t4.z); tm.w = fminf(tm.w, t4.w);
            idx0 += (size_t)hstride;
        }
        *reinterpret_cast<float4*>(&sh_p[(r << 5) + c0]) = pm;
        *reinterpret_cast<float4*>(&sh_t[(r << 5) + c0]) = tm;
    }
    __syncthreads();

    unsigned char* mA = sh_seg;
    unsigned char* mB = (unsigned char*)sh_idx;
    for (int pix = tid; pix < NNODE; pix += BLOCK)
        mA[pix] = (sh_t[pix] == 0.0f) ? 1 : 0;
    __syncthreads();
    for (int it = 0; it < 5; ++it) {
        unsigned char* src = (it & 1) ? mB : mA;
        unsigned char* dst = (it & 1) ? mA : mB;
        for (int pix = tid; pix < NNODE; pix += BLOCK) {
            const int r = pix >> 5, c = pix & 31;
            unsigned char v = src[pix];
            if (r > 0)  v |= src[pix - 32];
            if (r < 31) v |= src[pix + 32];
            if (c > 0)  v |= src[pix - 1];
            if (c < 31) v |= src[pix + 1];
            dst[pix] = v;
        }
        __syncthreads();
    }
    for (int pix = tid; pix < NNODE; pix += BLOCK)
        mA[pix] = mB[pix] ^ 1;
    __syncthreads();

    for (int pix = tid; pix < NNODE; pix += BLOCK)
        sh_parent[pix] = mA[pix] ? (unsigned short)pix : (unsigned short)0xFFFF;
    __syncthreads();
    for (;;) {
        int changed = 0;
        for (int pix = tid; pix < NNODE; pix += BLOCK) {
            if (!mA[pix]) continue;
            const int r = pix >> 5, c = pix & 31;
            int m = sh_parent[pix];
            #pragma unroll
            for (int d = 0; d < 8; ++d) {
                static const int dr[8] = {-1,-1,-1, 0, 0, 1, 1, 1};
                static const int dc[8] = {-1, 0, 1,-1, 1,-1, 0, 1};
                const int rr = r + dr[d], cc = c + dc[d];
                if (rr < 0 || rr > 31 || cc < 0 || cc > 31) continue;
                const int nb = (rr << 5) + cc;
                if (mA[nb]) { int v = sh_parent[nb]; if (v < m) m = v; }
            }
            while ((int)sh_parent[m] < m) m = sh_parent[m];
            if (m < (int)sh_parent[pix]) { sh_parent[pix] = (unsigned short)m; changed = 1; }
        }
        if (!__syncthreads_or(changed)) break;
    }

    if (tid == 0) sh_L = 0;
    __syncthreads();
    for (int pix = tid; pix < NNODE; pix += BLOCK) {
        if (mA[pix] && (int)sh_parent[pix] == pix) {
            const int id = atomicAdd(&sh_L, 1);
            sh_szto[pix] = (unsigned int)(id + 1);
        }
    }
    __syncthreads();
    for (int pix = tid; pix < NNODE; pix += BLOCK) {
        unsigned char s = 0;
        if (mA[pix]) {
            int lab = (int)sh_szto[sh_parent[pix]];
            if (lab > 255) lab = 255;
            s = (unsigned char)lab;
        }
        sh_seg[pix] = s;
    }
    __syncthreads();

    const int Lraw = sh_L;
    const int mode = (Lraw <= 1) ? 0 : ((Lraw <= 4) ? 1 : 2);
    const bool skip_all = (Lraw == 0) || (Lraw == 1 && sign == 0);

    if (!skip_all) {

    if (mode == 0)      uf_init<0>(sh_parent, sh_szto, sh_cnt64, sh_seg, tid);
    else if (mode == 1) uf_init<1>(sh_parent, sh_szto, sh_cnt64, sh_seg, tid);
    else                uf_init<2>(sh_parent, sh_szto, sh_cnt64, sh_seg, tid);
    __syncthreads();

    unsigned int   K[8];
    unsigned short I[8];
    const int b8 = tid << 3;
    #pragma unroll
    for (int l = 0; l < 8; ++l) {
        const int e = b8 + l;
        if (e < NE) {
            int a, bb; edge_nodes(e, a, bb);
            float cost = sh_p[a] + sh_p[bb];
            const float g = sh_t[a] + sh_t[bb];
            if (sign == 0) { if (g > 10.0f) cost = 10.0f; }
            else           { if (g <  3.0f) cost = 0.0f;  }
            K[l] = ~__float_as_uint(cost);
            I[l] = (unsigned short)e;
        } else {
            K[l] = 0xFFFFFFFFu;
            I[l] = (unsigned short)0xFFFF;
        }
    }
    cswap(K[0],I[0],K[1],I[1], true );
    cswap(K[2],I[2],K[3],I[3], false);
    cswap(K[4],I[4],K[5],I[5], true );
    cswap(K[6],I[6],K[7],I[7], false);
    cswap(K[0],I[0],K[2],I[2], true );
    cswap(K[1],I[1],K[3],I[3], true );
    cswap(K[4],I[4],K[6],I[6], false);
    cswap(K[5],I[5],K[7],I[7], false);
    cswap(K[0],I[0],K[1],I[1], true );
    cswap(K[2],I[2],K[3],I[3], true );
    cswap(K[4],I[4],K[5],I[5], false);
    cswap(K[6],I[6],K[7],I[7], false);
    {
        const bool u8 = ((b8 & 8) == 0);
        cswap(K[0],I[0],K[4],I[4], u8); cswap(K[1],I[1],K[5],I[5], u8);
        cswap(K[2],I[2],K[6],I[6], u8); cswap(K[3],I[3],K[7],I[7], u8);
        cswap(K[0],I[0],K[2],I[2], u8); cswap(K[1],I[1],K[3],I[3], u8);
        cswap(K[4],I[4],K[6],I[6], u8); cswap(K[5],I[5],K[7],I[7], u8);
        cswap(K[0],I[0],K[1],I[1], u8); cswap(K[2],I[2],K[3],I[3], u8);
        cswap(K[4],I[4],K[5],I[5], u8); cswap(K[6],I[6],K[7],I[7], u8);
    }
    {
        uint4 k0, k1, iv;
        k0.x=K[0]; k0.y=K[1]; k0.z=K[2]; k0.w=K[3];
        k1.x=K[4]; k1.y=K[5]; k1.z=K[6]; k1.w=K[7];
        iv.x=(unsigned int)I[0] | ((unsigned int)I[1]<<16);
        iv.y=(unsigned int)I[2] | ((unsigned int)I[3]<<16);
        iv.z=(unsigned int)I[4] | ((unsigned int)I[5]<<16);
        iv.w=(unsigned int)I[6] | ((unsigned int)I[7]<<16);
        *reinterpret_cast<uint4*>(&sh_key[b8])     = k0;
        *reinterpret_cast<uint4*>(&sh_key[b8 + 4]) = k1;
        *reinterpret_cast<uint4*>(&sh_idx[b8])     = iv;
    }
    __syncthreads();

    for (int k = 16; k <= NSORT; k <<= 1) {
        for (int j = k >> 1; j >= 8; j >>= 1) {
            for (int p = tid; p < (NSORT >> 1); p += BLOCK) {
                const int i   = ((p & ~(j - 1)) << 1) | (p & (j - 1));
                const int ixj = i | j;
                const unsigned int ka = sh_key[i], kb = sh_key[ixj];
                const unsigned short ia = sh_idx[i], ib = sh_idx[ixj];
                const bool gt = (ka > kb) || (ka == kb && ia > ib);
                const bool up = ((i & k) == 0);
                if (gt == up) {
                    sh_key[i] = kb; sh_key[ixj] = ka;
                    sh_idx[i] = ib; sh_idx[ixj] = ia;
                }
            }
            __syncthreads();
        }
        {
            const uint4 k0 = *reinterpret_cast<const uint4*>(&sh_key[b8]);
            const uint4 k1 = *reinterpret_cast<const uint4*>(&sh_key[b8 + 4]);
            const uint4 iv = *reinterpret_cast<const uint4*>(&sh_idx[b8]);
            K[0]=k0.x; K[1]=k0.y; K[2]=k0.z; K[3]=k0.w;
            K[4]=k1.x; K[5]=k1.y; K[6]=k1.z; K[7]=k1.w;
            I[0]=(unsigned short)(iv.x); I[1]=(unsigned short)(iv.x>>16);
            I[2]=(unsigned short)(iv.y); I[3]=(unsigned short)(iv.y>>16);
            I[4]=(unsigned short)(iv.z); I[5]=(unsigned short)(iv.z>>16);
            I[6]=(unsigned short)(iv.w); I[7]=(unsigned short)(iv.w>>16);
            const bool u8 = ((b8 & k) == 0);
            cswap(K[0],I[0],K[4],I[4], u8); cswap(K[1],I[1],K[5],I[5], u8);
            cswap(K[2],I[2],K[6],I[6], u8); cswap(K[3],I[3],K[7],I[7], u8);
            cswap(K[0],I[0],K[2],I[2], u8); cswap(K[1],I[1],K[3],I[3], u8);
            cswap(K[4],I[4],K[6],I[6], u8); cswap(K[5],I[5],K[7],I[7], u8);
            cswap(K[0],I[0],K[1],I[1], u8); cswap(K[2],I[2],K[3],I[3], u8);
            cswap(K[4],I[4],K[5],I[5], u8); cswap(K[6],I[6],K[7],I[7], u8);
            uint4 o0, o1, ov;
            o0.x=K[0]; o0.y=K[1]; o0.z=K[2]; o0.w=K[3];
            o1.x=K[4]; o1.y=K[5]; o1.z=K[6]; o1.w=K[7];
            ov.x=(unsigned int)I[0] | ((unsigned int)I[1]<<16);
            ov.y=(unsigned int)I[2] | ((unsigned int)I[3]<<16);
            ov.z=(unsigned int)I[4] | ((unsigned int)I[5]<<16);
            ov.w=(unsigned int)I[6] | ((unsigned int)I[7]<<16);
            *reinterpret_cast<uint4*>(&sh_key[b8])     = o0;
            *reinterpret_cast<uint4*>(&sh_key[b8 + 4]) = o1;
            *reinterpret_cast<uint4*>(&sh_idx[b8])     = ov;
        }
        __syncthreads();
    }

    for (int e = tid; e < NE; e += BLOCK) sh_key[e] = 0u;
    __syncthreads();

    if (tid < 64) {
        if (mode == 0)      kruskal_run<0>(sh_parent, sh_szto, sh_cnt64, sh_key, sh_idx, sign, tid);
        else if (mode == 1) kruskal_run<1>(sh_parent, sh_szto, sh_cnt64, sh_key, sh_idx, sign, tid);
        else                kruskal_run<2>(sh_parent, sh_szto, sh_cnt64, sh_key, sh_idx, sign, tid);
    }
    __syncthreads();

    {
        float part = 0.0f;
        for (int e = tid; e < NE; e += BLOCK) part += __uint_as_float(sh_key[e]);
        for (int off = 32; off > 0; off >>= 1) part += __shfl_down(part, off, 64);
        if ((tid & 63) == 0) sh_red[tid >> 6] = (double)part;
        __syncthreads();
        if (tid == 0) sh_sn = (float)(sh_red[0] + sh_red[1] + sh_red[2] + sh_red[3]);
        __syncthreads();
    }
    const float sn = sh_sn;

    double acc = 0.0;
    for (int pix = tid; pix < NNODE; pix += BLOCK) {
        const int r = pix >> 5, c = pix & 31;
        float nw = 0.0f;
        if (c < 31) { const int e = r * 31 + c;
            float v = __uint_as_float(sh_key[e]); if (sn > 0.0f) v = v / sn;
            const float g = sh_t[pix] + sh_t[pix + 1];
            if (sign == 0) { if (g >= 3.0f) v = 0.0f; } else { if (g < 10.0f) v = 0.0f; }
            nw += v; }
        if (c > 0)  { const int e = r * 31 + c - 1;
            float v = __uint_as_float(sh_key[e]); if (sn > 0.0f) v = v / sn;
            const float g = sh_t[pix - 1] + sh_t[pix];
            if (sign == 0) { if (g >= 3.0f) v = 0.0f; } else { if (g < 10.0f) v = 0.0f; }
            nw += v; }
        if (r < 31) { const int e = NH + pix;
            float v = __uint_as_float(sh_key[e]); if (sn > 0.0f) v = v / sn;
            const float g = sh_t[pix] + sh_t[pix + 32];
            if (sign == 0) { if (g >= 3.0f) v = 0.0f; } else { if (g < 10.0f) v = 0.0f; }
            nw += v; }
        if (r > 0)  { const int e = NH + pix - 32;
            float v = __uint_as_float(sh_key[e]); if (sn > 0.0f) v = v / sn;
            const float g = sh_t[pix - 32] + sh_t[pix];
            if (sign == 0) { if (g >= 3.0f) v = 0.0f; } else { if (g < 10.0f) v = 0.0f; }
            nw += v; }
        const float p = sh_p[pix];
        float term;
        if (sign == 0) term = (p * p) * nw;
        else { const float d = 20.0f - p; term = (0.1f * (d * d)) * nw; }
        acc += (double)term;
    }
    for (int off = 32; off > 0; off >>= 1) acc += __shfl_down(acc, off, 64);
    if ((tid & 63) == 0) sh_red[tid >> 6] = acc;
    __syncthreads();
    if (tid == 0)
        atomicAdd(&acc_ws[1], sh_red[0] + sh_red[1] + sh_red[2] + sh_red[3]);

    } // !skip_all
}

__global__ __launch_bounds__(BLOCK) void mse_kernel(const float* __restrict__ pred,
                                                    const float* __restrict__ tgt,
                                                    double* __restrict__ acc_ws,
                                                    long n) {
    double acc = 0.0;
    for (long i = (long)blockIdx.x * BLOCK + threadIdx.x; i < n; i += (long)gridDim.x * BLOCK) {
        const float d = pred[i] - tgt[i];
        acc += (double)(d * d);
    }
    for (int off = 32; off > 0; off >>= 1) acc += __shfl_down(acc, off, 64);
    __shared__ double red[4];
    if ((threadIdx.x & 63) == 0) red[threadIdx.x >> 6] = acc;
    __syncthreads();
    if (threadIdx.x == 0)
        atomicAdd(&acc_ws[0], red[0] + red[1] + red[2] + red[3]);
}

__global__ void fin_kernel(const double* __restrict__ acc_ws, float* __restrict__ out, long n) {
    if (threadIdx.x == 0 && blockIdx.x == 0) {
        out[0] = (float)(acc_ws[0] / (double)n);
        out[1] = (float)(acc_ws[1] * (double)1e-4f);
    }
}

extern "C" void kernel_launch(void* const* d_in, const int* in_sizes, int n_in,
                              void* d_out, int out_size, void* d_ws, size_t ws_size,
                              hipStream_t stream) {
    const float* pred = (const float*)d_in[0];
    const float* tgt  = (const float*)d_in[1];
    float* out = (float*)d_out;
    double* acc = (double*)d_ws;

    const long n = (long)in_sizes[0];            // 4*1*128*128*128 = 8388608
    const int  B = (int)(n / 2097152);           // batches
    const int  NW = 96 * B;                      // prep work items
    const size_t need = 64 + (size_t)NW * NNODE * 9 + (size_t)NW * 4;

    hipMemsetAsync(d_ws, 0, 2 * sizeof(double), stream);
    if (ws_size >= need) {
        prep_kernel<<<NW, BLOCK, 0, stream>>>(pred, tgt, (char*)d_ws, acc, B);
        solve_kernel<<<192 * B, BLOCK, 0, stream>>>((const char*)d_ws, acc, B);
    } else {
        mse_kernel<<<1024, BLOCK, 0, stream>>>(pred, tgt, acc, n);
        conn_kernel<<<192 * B, BLOCK, 0, stream>>>(pred, tgt, acc, B);
    }
    fin_kernel<<<1, 64, 0, stream>>>(acc, out, n);
}

// Round 15
// 492.303 us; speedup vs baseline: 1.2656x; 1.2656x over previous
//
#include <hip/hip_runtime.h>

#define BLOCK 256
#define NNODE 1024
#define NH    992
#define NE    1984
#define NSORT 2048
#define LMAX  12
#define CHUNK 64
#define NPASS (NE / CHUNK)

typedef unsigned long long ull;

__device__ __forceinline__ void edge_nodes(int e, int& a, int& b) {
    if (e < NH) {                 // horizontal: (r,c)-(r,c+1), e = r*31+c
        int r = e / 31;
        int c = e - r * 31;
        a = (r << 5) + c;
        b = a + 1;
    } else {                      // vertical: (r,c)-(r+1,c), e-992 = r*32+c
        a = e - NH;
        b = a + 32;
    }
}

__device__ __forceinline__ int find_par(unsigned short* par, int x) {
    volatile unsigned short* vp = par;
    int r = x;
    int p = vp[r];
    while (p != r) { r = p; p = vp[r]; }
    int c = x;
    while (c != r) { const int nxt = vp[c]; vp[c] = (unsigned short)r; c = nxt; }
    return r;
}

__device__ __forceinline__ int dot16x4(ull a, ull b) {
    int s  = (int)(a & 0xFFFFu)         * (int)(b & 0xFFFFu);
    s     += (int)((a >> 16) & 0xFFFFu) * (int)((b >> 16) & 0xFFFFu);
    s     += (int)((a >> 32) & 0xFFFFu) * (int)((b >> 32) & 0xFFFFu);
    s     += (int)((a >> 48) & 0xFFFFu) * (int)((b >> 48) & 0xFFFFu);
    return s;
}

__device__ __forceinline__ void cswap(unsigned int& ka, unsigned short& ia,
                                      unsigned int& kb, unsigned short& ib, bool up) {
    const bool gt = (ka > kb) || (ka == kb && ia > ib);
    if (gt == up) {
        const unsigned int  tk = ka; ka = kb; kb = tk;
        const unsigned short ti = ia; ia = ib; ib = ti;
    }
}

// ----------------------------------------------------------------------------
// Hybrid Kruskal (wave 0) — r13 structure EXACTLY (register-maintained roots,
// pack recomputed per iteration, NO per-iteration LDS re-find). Single diff:
// the wave-uniform broadcast uses v_readlane (VALU, ~10cy) instead of
// ds_bpermute (~120cy LDS pipe); legal because i = ctz(ballot) is uniform.
// Per 64-edge pass (MODE<=1):
//  (a) ONE claim round: candidate lanes atomicMax both roots with tag
//      ((pass+1)<<6)|(63-lane): max tag == MIN lane; tags monotone over passes
//      so stale tags always lose -> no reset needed.
//  (b) winners (own both claims) == greedy prefix-independent set -> commit
//      IN PARALLEL per-lane (mutually disjoint; exact serial-prefix state).
//  (c) losers re-find once and run the serial loop (readlane pack,
//      wave-uniform state loads, register-maintained roots).
// Claims alias unused sh_cnt64 words: MODE 0 -> u32[node]; MODE 1 -> u32 at
// node*6+2 (low half of unused word-1). MODE 2 (L>=5, rare) is pure serial.
// ----------------------------------------------------------------------------
template<int MODE>
__device__ __forceinline__ void kruskal_run(unsigned short* sh_parent,
                                            unsigned int*   sh_szto,
                                            ull*            sh_cnt64,
                                            unsigned int*   sh_key,
                                            const unsigned short* sh_idx,
                                            const int sign, const int lane) {
    unsigned int* claim32 = (unsigned int*)sh_cnt64;
    for (int pass = 0; pass < NPASS; ++pass) {
        const int e = sh_idx[pass * CHUNK + lane];
        int a, bb; edge_nodes(e, a, bb);
        int ra = find_par(sh_parent, a);
        int rb = find_par(sh_parent, bb);
        bool cand = (ra != rb);

        if (MODE <= 1) {
            const unsigned int tag = ((unsigned int)(pass + 1) << 6) | (unsigned int)(63 - lane);
            const int ia = (MODE == 0) ? ra : (ra * 6 + 2);
            const int ib = (MODE == 0) ? rb : (rb * 6 + 2);
            if (cand) {
                atomicMax(&claim32[ia], tag);
                atomicMax(&claim32[ib], tag);
            }
            asm volatile("s_waitcnt lgkmcnt(0)" ::: "memory");
            __builtin_amdgcn_sched_barrier(0);
            bool win = false;
            if (cand) win = (claim32[ia] == tag) && (claim32[ib] == tag);
            if (win) {
                // parallel commit: winners' root pairs are mutually disjoint
                const unsigned int xa = sh_szto[ra], xb = sh_szto[rb];
                const int ta = (int)(xa >> 16), tb = (int)(xb >> 16);
                int wv;
                ull a0 = 0, b0 = 0;
                if (MODE == 0) {
                    wv = ta * tb;                 // L==1: same == ta*tb
                } else {
                    a0 = sh_cnt64[ra * 3]; b0 = sh_cnt64[rb * 3];
                    const int same = dot16x4(a0, b0);
                    wv = sign ? same : (ta * tb - same);
                }
                const int big = ((xa & 0xFFFFu) > (xb & 0xFFFFu));
                const int rs = big ? ra : rb;     // survivor (union by size)
                const int rl = big ? rb : ra;
                sh_key[e] = __float_as_uint((float)wv);
                sh_szto[rs] = xa + xb;            // sums <= 2048: no field carry
                if (MODE == 1) sh_cnt64[rs * 3] = a0 + b0;  // per-lane sums <= 1024
                sh_parent[rl] = (unsigned short)rs;
                cand = false;                     // handled
            }
            asm volatile("s_waitcnt lgkmcnt(0)" ::: "memory");
            __builtin_amdgcn_sched_barrier(0);
            if (cand) {                           // tail: re-find post-winners
                ra = find_par(sh_parent, ra);
                rb = find_par(sh_parent, rb);
                cand = (ra != rb);
            }
        }

        // ---- serial tail (readlane pack, wave-uniform state loads,
        //      register-maintained roots) ----
        ull m = __ballot(cand);
        while (m) {
            const int i = (int)__builtin_ctzll(m);
            m &= m - 1;
            // pack from CURRENT (register-updated) roots; i is wave-uniform
            const unsigned int pack = (unsigned int)ra | ((unsigned int)rb << 10) | ((unsigned int)e << 20);
            const unsigned int pk = (unsigned int)__builtin_amdgcn_readlane((int)pack, i);
            const int ra_i = (int)(pk & 1023u);
            const int rb_i = (int)((pk >> 10) & 1023u);
            if (ra_i == rb_i) continue;           // became a cycle mid-pass
            const int se = (int)(pk >> 20);
            const unsigned int xa = sh_szto[ra_i], xb = sh_szto[rb_i];
            const int ta = (int)(xa >> 16), tb = (int)(xb >> 16);
            const int big = ((xa & 0xFFFFu) > (xb & 0xFFFFu));
            const int rs = big ? ra_i : rb_i;
            const int rl = big ? rb_i : ra_i;
            int wv;
            if (MODE == 0) {
                wv = ta * tb;
            } else if (MODE == 1) {
                const ull a0 = sh_cnt64[ra_i * 3];
                const ull b0 = sh_cnt64[rb_i * 3];
                const int same = dot16x4(a0, b0);
                wv = sign ? same : (ta * tb - same);
                if (lane == 0 && (ta + tb) > 0)
                    sh_cnt64[rs * 3] = a0 + b0;
            } else {
                const ull a0 = sh_cnt64[ra_i * 3 + 0];
                const ull a1 = sh_cnt64[ra_i * 3 + 1];
                const ull a2 = sh_cnt64[ra_i * 3 + 2];
                const ull b0 = sh_cnt64[rb_i * 3 + 0];
                const ull b1 = sh_cnt64[rb_i * 3 + 1];
                const ull b2 = sh_cnt64[rb_i * 3 + 2];
                const int same = dot16x4(a0, b0) + dot16x4(a1, b1) + dot16x4(a2, b2);
                wv = sign ? same : (ta * tb - same);
                if (lane == 0 && (ta + tb) > 0) {
                    sh_cnt64[rs * 3 + 0] = a0 + b0;
                    sh_cnt64[rs * 3 + 1] = a1 + b1;
                    sh_cnt64[rs * 3 + 2] = a2 + b2;
                }
            }
            if (lane == 0) {
                sh_key[se] = __float_as_uint((float)wv);
                sh_szto[rs] = xa + xb;
                sh_parent[rl] = (unsigned short)rs;
            }
            // every lane tracks the merge in registers (keeps pack current)
            if (ra == rl) ra = rs;
            if (rb == rl) rb = rs;
        }
    }
}

// shared UF init (claims zeroed in the aliased words)
template<int MODE>
__device__ __forceinline__ void uf_init(unsigned short* sh_parent,
                                        unsigned int* sh_szto,
                                        ull* sh_cnt64,
                                        const unsigned char* sh_seg,
                                        const int tid) {
    unsigned int* claim32 = (unsigned int*)sh_cnt64;
    for (int pix = tid; pix < NNODE; pix += BLOCK) {
        sh_parent[pix] = (unsigned short)pix;
        const int s = sh_seg[pix];
        const unsigned int tot = (s > 0 && s <= LMAX) ? 1u : 0u;
        sh_szto[pix] = 1u | (tot << 16);
        if (MODE == 0) {
            claim32[pix] = 0u;                    // claim array
        } else {
            ull c0 = 0, c1 = 0, c2 = 0;
            if (s >= 1 && s <= LMAX) {
                const ull bit = 1ull << (((s - 1) & 3) * 16);
                const int q = (s - 1) >> 2;
                if (q == 0) c0 = bit; else if (q == 1) c1 = bit; else c2 = bit;
            }
            sh_cnt64[pix * 3 + 0] = c0;
            sh_cnt64[pix * 3 + 1] = (MODE == 1) ? 0ull : c1;   // mode1: claim word
            if (MODE == 2) sh_cnt64[pix * 3 + 2] = c2;
        }
    }
}

// ============================================================================
// prep_kernel: one block per (item, win, b). Projection + dilate + CC + label.
// axis_id==2 blocks additionally accumulate the MSE (each voxel exactly once).
// ============================================================================
__global__ __launch_bounds__(BLOCK) void prep_kernel(const float* __restrict__ pred,
                                                     const float* __restrict__ tgt,
                                                     char* __restrict__ ws,
                                                     double* __restrict__ acc_ws,
                                                     int B) {
    __shared__ alignas(16) float sh_p[NNODE];
    __shared__ alignas(16) float sh_t[NNODE];
    __shared__ unsigned char  mA[NNODE];
    __shared__ unsigned char  mB[NNODE];
    __shared__ unsigned short sh_parent[NNODE];
    __shared__ unsigned short sh_lab[NNODE];
    __shared__ int sh_L;
    __shared__ double sh_redp[4];

    const int tid = threadIdx.x;
    const int w = blockIdx.x;                         // work index
    int wg = w;
    const int b    = wg % B;  wg /= B;
    const int win  = wg & 3;  wg >>= 2;
    const int item = wg;                              // 0..23
    const int axis_id = item % 3;
    const int cube = item / 3;
    const int ci = cube & 1;
    const int cj = (cube >> 1) & 1;
    const int ck = (cube >> 2) & 1;
    const int wk = win >> 1;
    const int wj = win & 1;

    const int NW = 96 * B;
    float* Pb = (float*)(ws + 64);
    float* Tb = Pb + (size_t)NW * NNODE;
    unsigned char* Sb = (unsigned char*)(Tb + (size_t)NW * NNODE);
    int* Lb = (int*)(Sb + (size_t)NW * NNODE);

    const size_t base = (size_t)b * 2097152u;

    // ---- projection mins (32x32 window of the 64x64 projection) ----
    if (axis_id == 2) {
        // contiguous along the reduced axis: float4 loads; also accumulate MSE
        double msum = 0.0;
        for (int pix = tid; pix < NNODE; pix += BLOCK) {
            const int r = pix >> 5, c = pix & 31;
            const int R = wk * 32 + r, C = wj * 32 + c;
            const size_t idx0 = base + (size_t)(ck * 64 + R) * 16384u + (size_t)(cj * 64 + C) * 128u + (size_t)(ci * 64);
            const float4* pp = reinterpret_cast<const float4*>(pred + idx0);
            const float4* tp = reinterpret_cast<const float4*>(tgt + idx0);
            float pm = 3.4e38f, tm = 3.4e38f;
            #pragma unroll
            for (int h = 0; h < 16; ++h) {
                const float4 a = pp[h];
                const float4 t = tp[h];
                pm = fminf(pm, fminf(fminf(a.x, a.y), fminf(a.z, a.w)));
                tm = fminf(tm, fminf(fminf(t.x, t.y), fminf(t.z, t.w)));
                const float dx = a.x - t.x, dy = a.y - t.y;
                const float dz = a.z - t.z, dw = a.w - t.w;
                msum += (double)(dx * dx);
                msum += (double)(dy * dy);
                msum += (double)(dz * dz);
                msum += (double)(dw * dw);
            }
            sh_p[pix] = pm;
            sh_t[pix] = tm;
        }
        for (int off = 32; off > 0; off >>= 1) msum += __shfl_down(msum, off, 64);
        if ((tid & 63) == 0) sh_redp[tid >> 6] = msum;
        __syncthreads();
        if (tid == 0)
            atomicAdd(&acc_ws[0], sh_redp[0] + sh_redp[1] + sh_redp[2] + sh_redp[3]);
    } else {
        const int r  = tid >> 3;
        const int c0 = (tid & 7) << 2;
        const int R = wk * 32 + r, C = wj * 32 + c0;
        size_t idx0; int hstride;
        if (axis_id == 0) {
            idx0 = base + (size_t)(ck * 64) * 16384u + (size_t)(cj * 64 + R) * 128u + (size_t)(ci * 64 + C);
            hstride = 16384;
        } else {
            idx0 = base + (size_t)(ck * 64 + R) * 16384u + (size_t)(cj * 64) * 128u + (size_t)(ci * 64 + C);
            hstride = 128;
        }
        float4 pm = make_float4(3.4e38f, 3.4e38f, 3.4e38f, 3.4e38f);
        float4 tm = pm;
        #pragma unroll 8
        for (int h = 0; h < 64; ++h) {
            const float4 a  = *reinterpret_cast<const float4*>(pred + idx0);
            const float4 t4 = *reinterpret_cast<const float4*>(tgt + idx0);
            pm.x = fminf(pm.x, a.x);  pm.y = fminf(pm.y, a.y);
            pm.z = fminf(pm.z, a.z);  pm.w = fminf(pm.w, a.w);
            tm.x = fminf(tm.x, t4.x); tm.y = fminf(tm.y, t4.y);
            tm.z = fminf(tm.z, t4.z); tm.w = fminf(tm.w, t4.w);
            idx0 += (size_t)hstride;
        }
        *reinterpret_cast<float4*>(&sh_p[(r << 5) + c0]) = pm;
        *reinterpret_cast<float4*>(&sh_t[(r << 5) + c0]) = tm;
        __syncthreads();
    }

    // ---- dilate5 of (t == 0), von Neumann, zero padded, window-local ----
    for (int pix = tid; pix < NNODE; pix += BLOCK)
        mA[pix] = (sh_t[pix] == 0.0f) ? 1 : 0;
    __syncthreads();
    for (int it = 0; it < 5; ++it) {
        unsigned char* src = (it & 1) ? mB : mA;
        unsigned char* dst = (it & 1) ? mA : mB;
        for (int pix = tid; pix < NNODE; pix += BLOCK) {
            const int r = pix >> 5, c = pix & 31;
            unsigned char v = src[pix];
            if (r > 0)  v |= src[pix - 32];
            if (r < 31) v |= src[pix + 32];
            if (c > 0)  v |= src[pix - 1];
            if (c < 31) v |= src[pix + 1];
            dst[pix] = v;
        }
        __syncthreads();
    }
    for (int pix = tid; pix < NNODE; pix += BLOCK)
        mA[pix] = mB[pix] ^ 1;                        // fg
    __syncthreads();

    // ---- 8-connected CC labeling on fg via min-index propagation ----
    for (int pix = tid; pix < NNODE; pix += BLOCK)
        sh_parent[pix] = mA[pix] ? (unsigned short)pix : (unsigned short)0xFFFF;
    __syncthreads();
    for (;;) {
        int changed = 0;
        for (int pix = tid; pix < NNODE; pix += BLOCK) {
            if (!mA[pix]) continue;
            const int r = pix >> 5, c = pix & 31;
            int m = sh_parent[pix];
            #pragma unroll
            for (int d = 0; d < 8; ++d) {
                static const int dr[8] = {-1,-1,-1, 0, 0, 1, 1, 1};
                static const int dc[8] = {-1, 0, 1,-1, 1,-1, 0, 1};
                const int rr = r + dr[d], cc = c + dc[d];
                if (rr < 0 || rr > 31 || cc < 0 || cc > 31) continue;
                const int nb = (rr << 5) + cc;
                if (mA[nb]) { int v = sh_parent[nb]; if (v < m) m = v; }
            }
            while ((int)sh_parent[m] < m) m = sh_parent[m];
            if (m < (int)sh_parent[pix]) { sh_parent[pix] = (unsigned short)m; changed = 1; }
        }
        if (!__syncthreads_or(changed)) break;
    }

    // ---- compact labels ----
    if (tid == 0) sh_L = 0;
    __syncthreads();
    for (int pix = tid; pix < NNODE; pix += BLOCK) {
        if (mA[pix] && (int)sh_parent[pix] == pix) {
            const int id = atomicAdd(&sh_L, 1);
            sh_lab[pix] = (unsigned short)(id + 1);
        }
    }
    __syncthreads();

    // ---- write P, T, SEG, L to workspace (coalesced) ----
    {
        const int p4 = tid << 2;                      // exactly one float4 per thread
        *reinterpret_cast<float4*>(&Pb[(size_t)w * NNODE + p4]) =
            *reinterpret_cast<const float4*>(&sh_p[p4]);
        *reinterpret_cast<float4*>(&Tb[(size_t)w * NNODE + p4]) =
            *reinterpret_cast<const float4*>(&sh_t[p4]);
        unsigned int packed = 0;
        #pragma unroll
        for (int q = 0; q < 4; ++q) {
            const int pix = p4 + q;
            unsigned int s = 0;
            if (mA[pix]) {
                int lab = sh_lab[sh_parent[pix]];
                if (lab > 255) lab = 255;
                s = (unsigned int)lab;
            }
            packed |= s << (q * 8);
        }
        ((unsigned int*)Sb)[(size_t)w * (NNODE / 4) + tid] = packed;
        if (tid == 0) Lb[w] = sh_L;
    }
}

// ============================================================================
// solve_kernel: one block per (sign, item, win, b). Reads P/T/SEG/L; skips
// exact-zero blocks instantly; key-build + sort + hybrid Kruskal + gather.
// ============================================================================
__global__ __launch_bounds__(BLOCK) void solve_kernel(const char* __restrict__ ws_c,
                                                      double* __restrict__ acc_ws,
                                                      int B) {
    __shared__ alignas(16) float          sh_p[NNODE];
    __shared__ alignas(16) float          sh_t[NNODE];
    __shared__ alignas(16) unsigned int   sh_key[NSORT];
    __shared__ alignas(16) unsigned short sh_idx[NSORT];
    __shared__ unsigned short sh_parent[NNODE];
    __shared__ unsigned int   sh_szto[NNODE];
    __shared__ ull            sh_cnt64[NNODE * 3];
    __shared__ alignas(16) unsigned char sh_seg[NNODE];
    __shared__ float          sh_sn;
    __shared__ double         sh_red[4];

    const int tid = threadIdx.x;
    int wg = blockIdx.x;
    const int sign = wg & 1;  wg >>= 1;
    const int w = wg;                                  // work index 0..96B-1

    const int NW = 96 * B;
    const float* Pb = (const float*)(ws_c + 64);
    const float* Tb = Pb + (size_t)NW * NNODE;
    const unsigned char* Sb = (const unsigned char*)(Tb + (size_t)NW * NNODE);
    const int* Lb = (const int*)(Sb + (size_t)NW * NNODE);

    // ---- skip check before touching LDS ----
    const int Lraw = Lb[w];
    if (Lraw == 0 || (Lraw == 1 && sign == 0)) return;   // exact-zero contribution
    const int mode = (Lraw <= 1) ? 0 : ((Lraw <= 4) ? 1 : 2);

    // ---- load P/T/SEG (one float4 / u32 per thread) ----
    {
        const int p4 = tid << 2;
        *reinterpret_cast<float4*>(&sh_p[p4]) =
            *reinterpret_cast<const float4*>(&Pb[(size_t)w * NNODE + p4]);
        *reinterpret_cast<float4*>(&sh_t[p4]) =
            *reinterpret_cast<const float4*>(&Tb[(size_t)w * NNODE + p4]);
        ((unsigned int*)sh_seg)[tid] =
            ((const unsigned int*)Sb)[(size_t)w * (NNODE / 4) + tid];
    }
    __syncthreads();

    // ---- union-find init (incl. claim zeroing) ----
    if (mode == 0)      uf_init<0>(sh_parent, sh_szto, sh_cnt64, sh_seg, tid);
    else if (mode == 1) uf_init<1>(sh_parent, sh_szto, sh_cnt64, sh_seg, tid);
    else                uf_init<2>(sh_parent, sh_szto, sh_cnt64, sh_seg, tid);
    __syncthreads();

    // ---- build sort keys in registers + k=2,4,8 rounds before first store ----
    unsigned int   K[8];
    unsigned short I[8];
    const int b8 = tid << 3;
    #pragma unroll
    for (int l = 0; l < 8; ++l) {
        const int e = b8 + l;
        if (e < NE) {
            int a, bb; edge_nodes(e, a, bb);
            float cost = sh_p[a] + sh_p[bb];
            const float g = sh_t[a] + sh_t[bb];
            if (sign == 0) { if (g > 10.0f) cost = 10.0f; }
            else           { if (g <  3.0f) cost = 0.0f;  }
            K[l] = ~__float_as_uint(cost);
            I[l] = (unsigned short)e;
        } else {
            K[l] = 0xFFFFFFFFu;
            I[l] = (unsigned short)0xFFFF;
        }
    }
    cswap(K[0],I[0],K[1],I[1], true );
    cswap(K[2],I[2],K[3],I[3], false);
    cswap(K[4],I[4],K[5],I[5], true );
    cswap(K[6],I[6],K[7],I[7], false);
    cswap(K[0],I[0],K[2],I[2], true );
    cswap(K[1],I[1],K[3],I[3], true );
    cswap(K[4],I[4],K[6],I[6], false);
    cswap(K[5],I[5],K[7],I[7], false);
    cswap(K[0],I[0],K[1],I[1], true );
    cswap(K[2],I[2],K[3],I[3], true );
    cswap(K[4],I[4],K[5],I[5], false);
    cswap(K[6],I[6],K[7],I[7], false);
    {
        const bool u8 = ((b8 & 8) == 0);
        cswap(K[0],I[0],K[4],I[4], u8); cswap(K[1],I[1],K[5],I[5], u8);
        cswap(K[2],I[2],K[6],I[6], u8); cswap(K[3],I[3],K[7],I[7], u8);
        cswap(K[0],I[0],K[2],I[2], u8); cswap(K[1],I[1],K[3],I[3], u8);
        cswap(K[4],I[4],K[6],I[6], u8); cswap(K[5],I[5],K[7],I[7], u8);
        cswap(K[0],I[0],K[1],I[1], u8); cswap(K[2],I[2],K[3],I[3], u8);
        cswap(K[4],I[4],K[5],I[5], u8); cswap(K[6],I[6],K[7],I[7], u8);
    }
    {
        uint4 k0, k1, iv;
        k0.x=K[0]; k0.y=K[1]; k0.z=K[2]; k0.w=K[3];
        k1.x=K[4]; k1.y=K[5]; k1.z=K[6]; k1.w=K[7];
        iv.x=(unsigned int)I[0] | ((unsigned int)I[1]<<16);
        iv.y=(unsigned int)I[2] | ((unsigned int)I[3]<<16);
        iv.z=(unsigned int)I[4] | ((unsigned int)I[5]<<16);
        iv.w=(unsigned int)I[6] | ((unsigned int)I[7]<<16);
        *reinterpret_cast<uint4*>(&sh_key[b8])     = k0;
        *reinterpret_cast<uint4*>(&sh_key[b8 + 4]) = k1;
        *reinterpret_cast<uint4*>(&sh_idx[b8])     = iv;
    }
    __syncthreads();

    // ---- bitonic k=16..2048: j>=8 via LDS pair-indexed, j=4,2,1 in registers ----
    for (int k = 16; k <= NSORT; k <<= 1) {
        for (int j = k >> 1; j >= 8; j >>= 1) {
            for (int p = tid; p < (NSORT >> 1); p += BLOCK) {
                const int i   = ((p & ~(j - 1)) << 1) | (p & (j - 1));
                const int ixj = i | j;
                const unsigned int ka = sh_key[i], kb = sh_key[ixj];
                const unsigned short ia = sh_idx[i], ib = sh_idx[ixj];
                const bool gt = (ka > kb) || (ka == kb && ia > ib);
                const bool up = ((i & k) == 0);
                if (gt == up) {
                    sh_key[i] = kb; sh_key[ixj] = ka;
                    sh_idx[i] = ib; sh_idx[ixj] = ia;
                }
            }
            __syncthreads();
        }
        {
            const uint4 k0 = *reinterpret_cast<const uint4*>(&sh_key[b8]);
            const uint4 k1 = *reinterpret_cast<const uint4*>(&sh_key[b8 + 4]);
            const uint4 iv = *reinterpret_cast<const uint4*>(&sh_idx[b8]);
            K[0]=k0.x; K[1]=k0.y; K[2]=k0.z; K[3]=k0.w;
            K[4]=k1.x; K[5]=k1.y; K[6]=k1.z; K[7]=k1.w;
            I[0]=(unsigned short)(iv.x); I[1]=(unsigned short)(iv.x>>16);
            I[2]=(unsigned short)(iv.y); I[3]=(unsigned short)(iv.y>>16);
            I[4]=(unsigned short)(iv.z); I[5]=(unsigned short)(iv.z>>16);
            I[6]=(unsigned short)(iv.w); I[7]=(unsigned short)(iv.w>>16);
            const bool u8 = ((b8 & k) == 0);
            cswap(K[0],I[0],K[4],I[4], u8); cswap(K[1],I[1],K[5],I[5], u8);
            cswap(K[2],I[2],K[6],I[6], u8); cswap(K[3],I[3],K[7],I[7], u8);
            cswap(K[0],I[0],K[2],I[2], u8); cswap(K[1],I[1],K[3],I[3], u8);
            cswap(K[4],I[4],K[6],I[6], u8); cswap(K[5],I[5],K[7],I[7], u8);
            cswap(K[0],I[0],K[1],I[1], u8); cswap(K[2],I[2],K[3],I[3], u8);
            cswap(K[4],I[4],K[5],I[5], u8); cswap(K[6],I[6],K[7],I[7], u8);
            uint4 o0, o1, ov;
            o0.x=K[0]; o0.y=K[1]; o0.z=K[2]; o0.w=K[3];
            o1.x=K[4]; o1.y=K[5]; o1.z=K[6]; o1.w=K[7];
            ov.x=(unsigned int)I[0] | ((unsigned int)I[1]<<16);
            ov.y=(unsigned int)I[2] | ((unsigned int)I[3]<<16);
            ov.z=(unsigned int)I[4] | ((unsigned int)I[5]<<16);
            ov.w=(unsigned int)I[6] | ((unsigned int)I[7]<<16);
            *reinterpret_cast<uint4*>(&sh_key[b8])     = o0;
            *reinterpret_cast<uint4*>(&sh_key[b8 + 4]) = o1;
            *reinterpret_cast<uint4*>(&sh_idx[b8])     = ov;
        }
        __syncthreads();
    }

    // ---- zero edge weights ----
    for (int e = tid; e < NE; e += BLOCK) sh_key[e] = 0u;
    __syncthreads();

    // ---- single-wave hybrid Kruskal (wave 0) ----
    if (tid < 64) {
        if (mode == 0)      kruskal_run<0>(sh_parent, sh_szto, sh_cnt64, sh_key, sh_idx, sign, tid);
        else if (mode == 1) kruskal_run<1>(sh_parent, sh_szto, sh_cnt64, sh_key, sh_idx, sign, tid);
        else                kruskal_run<2>(sh_parent, sh_szto, sh_cnt64, sh_key, sh_idx, sign, tid);
    }
    __syncthreads();

    // ---- normalization sum ----
    {
        float part = 0.0f;
        for (int e = tid; e < NE; e += BLOCK) part += __uint_as_float(sh_key[e]);
        for (int off = 32; off > 0; off >>= 1) part += __shfl_down(part, off, 64);
        if ((tid & 63) == 0) sh_red[tid >> 6] = (double)part;
        __syncthreads();
        if (tid == 0) sh_sn = (float)(sh_red[0] + sh_red[1] + sh_red[2] + sh_red[3]);
        __syncthreads();
    }
    const float sn = sh_sn;

    // ---- per-node gather + conn contribution ----
    double acc = 0.0;
    for (int pix = tid; pix < NNODE; pix += BLOCK) {
        const int r = pix >> 5, c = pix & 31;
        float nw = 0.0f;
        if (c < 31) { const int e = r * 31 + c;
            float v = __uint_as_float(sh_key[e]); if (sn > 0.0f) v = v / sn;
            const float g = sh_t[pix] + sh_t[pix + 1];
            if (sign == 0) { if (g >= 3.0f) v = 0.0f; } else { if (g < 10.0f) v = 0.0f; }
            nw += v; }
        if (c > 0)  { const int e = r * 31 + c - 1;
            float v = __uint_as_float(sh_key[e]); if (sn > 0.0f) v = v / sn;
            const float g = sh_t[pix - 1] + sh_t[pix];
            if (sign == 0) { if (g >= 3.0f) v = 0.0f; } else { if (g < 10.0f) v = 0.0f; }
            nw += v; }
        if (r < 31) { const int e = NH + pix;
            float v = __uint_as_float(sh_key[e]); if (sn > 0.0f) v = v / sn;
            const float g = sh_t[pix] + sh_t[pix + 32];
            if (sign == 0) { if (g >= 3.0f) v = 0.0f; } else { if (g < 10.0f) v = 0.0f; }
            nw += v; }
        if (r > 0)  { const int e = NH + pix - 32;
            float v = __uint_as_float(sh_key[e]); if (sn > 0.0f) v = v / sn;
            const float g = sh_t[pix - 32] + sh_t[pix];
            if (sign == 0) { if (g >= 3.0f) v = 0.0f; } else { if (g < 10.0f) v = 0.0f; }
            nw += v; }
        const float p = sh_p[pix];
        float term;
        if (sign == 0) term = (p * p) * nw;
        else { const float d = 20.0f - p; term = (0.1f * (d * d)) * nw; }
        acc += (double)term;
    }
    for (int off = 32; off > 0; off >>= 1) acc += __shfl_down(acc, off, 64);
    if ((tid & 63) == 0) sh_red[tid >> 6] = acc;
    __syncthreads();
    if (tid == 0)
        atomicAdd(&acc_ws[1], sh_red[0] + sh_red[1] + sh_red[2] + sh_red[3]);
}

// ============================================================================
// Fallback fused kernel — used only if the workspace is too small.
// ============================================================================
__global__ __launch_bounds__(BLOCK) void conn_kernel(const float* __restrict__ pred,
                                                     const float* __restrict__ tgt,
                                                     double* __restrict__ acc_ws,
                                                     int B) {
    __shared__ alignas(16) float          sh_p[NNODE];
    __shared__ alignas(16) float          sh_t[NNODE];
    __shared__ alignas(16) unsigned int   sh_key[NSORT];
    __shared__ alignas(16) unsigned short sh_idx[NSORT];
    __shared__ unsigned short sh_parent[NNODE];
    __shared__ unsigned int   sh_szto[NNODE];
    __shared__ ull            sh_cnt64[NNODE * 3];
    __shared__ unsigned char  sh_seg[NNODE];
    __shared__ int            sh_L;
    __shared__ float          sh_sn;
    __shared__ double         sh_red[4];

    const int tid = threadIdx.x;
    int wg = blockIdx.x;
    const int sign = (wg >> 3) & 1;
    wg = (wg & 7) | ((wg >> 4) << 3);
    const int b    = wg % B;  wg /= B;
    const int win  = wg & 3;  wg >>= 2;
    const int item = wg;
    const int axis_id = item % 3;
    const int cube = item / 3;
    const int ci = cube & 1;
    const int cj = (cube >> 1) & 1;
    const int ck = (cube >> 2) & 1;
    const int wk = win >> 1;
    const int wj = win & 1;

    const size_t base = (size_t)b * 2097152u;

    if (axis_id == 2) {
        for (int pix = tid; pix < NNODE; pix += BLOCK) {
            const int r = pix >> 5, c = pix & 31;
            const int R = wk * 32 + r, C = wj * 32 + c;
            const size_t idx0 = base + (size_t)(ck * 64 + R) * 16384u + (size_t)(cj * 64 + C) * 128u + (size_t)(ci * 64);
            const float4* pp = reinterpret_cast<const float4*>(pred + idx0);
            const float4* tp = reinterpret_cast<const float4*>(tgt + idx0);
            float pm = 3.4e38f, tm = 3.4e38f;
            #pragma unroll
            for (int h = 0; h < 16; ++h) {
                const float4 a = pp[h];
                const float4 t = tp[h];
                pm = fminf(pm, fminf(fminf(a.x, a.y), fminf(a.z, a.w)));
                tm = fminf(tm, fminf(fminf(t.x, t.y), fminf(t.z, t.w)));
            }
            sh_p[pix] = pm;
            sh_t[pix] = tm;
        }
    } else {
        const int r  = tid >> 3;
        const int c0 = (tid & 7) << 2;
        const int R = wk * 32 + r, C = wj * 32 + c0;
        size_t idx0; int hstride;
        if (axis_id == 0) {
            idx0 = base + (size_t)(ck * 64) * 16384u + (size_t)(cj * 64 + R) * 128u + (size_t)(ci * 64 + C);
            hstride = 16384;
        } else {
            idx0 = base + (size_t)(ck * 64 + R) * 16384u + (size_t)(cj * 64) * 128u + (size_t)(ci * 64 + C);
            hstride = 128;
        }
        float4 pm = make_float4(3.4e38f, 3.4e38f, 3.4e38f, 3.4e38f);
        float4 tm = pm;
        #pragma unroll 8
        for (int h = 0; h < 64; ++h) {
            const float4 a  = *reinterpret_cast<const float4*>(pred + idx0);
            const float4 t4 = *reinterpret_cast<const float4*>(tgt + idx0);
            pm.x = fminf(pm.x, a.x);  pm.y = fminf(pm.y, a.y);
            pm.z = fminf(pm.z, a.z);  pm.w = fminf(pm.w, a.w);
            tm.x = fminf(tm.x, t4.x); tm.y = fminf(tm.y, t4.y);
            tm.z = fminf(tm.z, t4.z); tm.w = fminf(tm.w, t4.w);
            idx0 += (size_t)hstride;
        }
        *reinterpret_cast<float4*>(&sh_p[(r << 5) + c0]) = pm;
        *reinterpret_cast<float4*>(&sh_t[(r << 5) + c0]) = tm;
    }
    __syncthreads();

    unsigned char* mA = sh_seg;
    unsigned char* mB = (unsigned char*)sh_idx;
    for (int pix = tid; pix < NNODE; pix += BLOCK)
        mA[pix] = (sh_t[pix] == 0.0f) ? 1 : 0;
    __syncthreads();
    for (int it = 0; it < 5; ++it) {
        unsigned char* src = (it & 1) ? mB : mA;
        unsigned char* dst = (it & 1) ? mA : mB;
        for (int pix = tid; pix < NNODE; pix += BLOCK) {
            const int r = pix >> 5, c = pix & 31;
            unsigned char v = src[pix];
            if (r > 0)  v |= src[pix - 32];
            if (r < 31) v |= src[pix + 32];
            if (c > 0)  v |= src[pix - 1];
            if (c < 31) v |= src[pix + 1];
            dst[pix] = v;
        }
        __syncthreads();
    }
    for (int pix = tid; pix < NNODE; pix += BLOCK)
        mA[pix] = mB[pix] ^ 1;
    __syncthreads();

    for (int pix = tid; pix < NNODE; pix += BLOCK)
        sh_parent[pix] = mA[pix] ? (unsigned short)pix : (unsigned short)0xFFFF;
    __syncthreads();
    for (;;) {
        int changed = 0;
        for (int pix = tid; pix < NNODE; pix += BLOCK) {
            if (!mA[pix]) continue;
            const int r = pix >> 5, c = pix & 31;
            int m = sh_parent[pix];
            #pragma unroll
            for (int d = 0; d < 8; ++d) {
                static const int dr[8] = {-1,-1,-1, 0, 0, 1, 1, 1};
                static const int dc[8] = {-1, 0, 1,-1, 1,-1, 0, 1};
                const int rr = r + dr[d], cc = c + dc[d];
                if (rr < 0 || rr > 31 || cc < 0 || cc > 31) continue;
                const int nb = (rr << 5) + cc;
                if (mA[nb]) { int v = sh_parent[nb]; if (v < m) m = v; }
            }
            while ((int)sh_parent[m] < m) m = sh_parent[m];
            if (m < (int)sh_parent[pix]) { sh_parent[pix] = (unsigned short)m; changed = 1; }
        }
        if (!__syncthreads_or(changed)) break;
    }

    if (tid == 0) sh_L = 0;
    __syncthreads();
    for (int pix = tid; pix < NNODE; pix += BLOCK) {
        if (mA[pix] && (int)sh_parent[pix] == pix) {
            const int id = atomicAdd(&sh_L, 1);
            sh_szto[pix] = (unsigned int)(id + 1);
        }
    }
    __syncthreads();
    for (int pix = tid; pix < NNODE; pix += BLOCK) {
        unsigned char s = 0;
        if (mA[pix]) {
            int lab = (int)sh_szto[sh_parent[pix]];
            if (lab > 255) lab = 255;
            s = (unsigned char)lab;
        }
        sh_seg[pix] = s;
    }
    __syncthreads();

    const int Lraw = sh_L;
    const int mode = (Lraw <= 1) ? 0 : ((Lraw <= 4) ? 1 : 2);
    const bool skip_all = (Lraw == 0) || (Lraw == 1 && sign == 0);

    if (!skip_all) {

    if (mode == 0)      uf_init<0>(sh_parent, sh_szto, sh_cnt64, sh_seg, tid);
    else if (mode == 1) uf_init<1>(sh_parent, sh_szto, sh_cnt64, sh_seg, tid);
    else                uf_init<2>(sh_parent, sh_szto, sh_cnt64, sh_seg, tid);
    __syncthreads();

    unsigned int   K[8];
    unsigned short I[8];
    const int b8 = tid << 3;
    #pragma unroll
    for (int l = 0; l < 8; ++l) {
        const int e = b8 + l;
        if (e < NE) {
            int a, bb; edge_nodes(e, a, bb);
            float cost = sh_p[a] + sh_p[bb];
            const float g = sh_t[a] + sh_t[bb];
            if (sign == 0) { if (g > 10.0f) cost = 10.0f; }
            else           { if (g <  3.0f) cost = 0.0f;  }
            K[l] = ~__float_as_uint(cost);
            I[l] = (unsigned short)e;
        } else {
            K[l] = 0xFFFFFFFFu;
            I[l] = (unsigned short)0xFFFF;
        }
    }
    cswap(K[0],I[0],K[1],I[1], true );
    cswap(K[2],I[2],K[3],I[3], false);
    cswap(K[4],I[4],K[5],I[5], true );
    cswap(K[6],I[6],K[7],I[7], false);
    cswap(K[0],I[0],K[2],I[2], true );
    cswap(K[1],I[1],K[3],I[3], true );
    cswap(K[4],I[4],K[6],I[6], false);
    cswap(K[5],I[5],K[7],I[7], false);
    cswap(K[0],I[0],K[1],I[1], true );
    cswap(K[2],I[2],K[3],I[3], true );
    cswap(K[4],I[4],K[5],I[5], false);
    cswap(K[6],I[6],K[7],I[7], false);
    {
        const bool u8 = ((b8 & 8) == 0);
        cswap(K[0],I[0],K[4],I[4], u8); cswap(K[1],I[1],K[5],I[5], u8);
        cswap(K[2],I[2],K[6],I[6], u8); cswap(K[3],I[3],K[7],I[7], u8);
        cswap(K[0],I[0],K[2],I[2], u8); cswap(K[1],I[1],K[3],I[3], u8);
        cswap(K[4],I[4],K[6],I[6], u8); cswap(K[5],I[5],K[7],I[7], u8);
        cswap(K[0],I[0],K[1],I[1], u8); cswap(K[2],I[2],K[3],I[3], u8);
        cswap(K[4],I[4],K[5],I[5], u8); cswap(K[6],I[6],K[7],I[7], u8);
    }
    {
        uint4 k0, k1, iv;
        k0.x=K[0]; k0.y=K[1]; k0.z=K[2]; k0.w=K[3];
        k1.x=K[4]; k1.y=K[5]; k1.z=K[6]; k1.w=K[7];
        iv.x=(unsigned int)I[0] | ((unsigned int)I[1]<<16);
        iv.y=(unsigned int)I[2] | ((unsigned int)I[3]<<16);
        iv.z=(unsigned int)I[4] | ((unsigned int)I[5]<<16);
        iv.w=(unsigned int)I[6] | ((unsigned int)I[7]<<16);
        *reinterpret_cast<uint4*>(&sh_key[b8])     = k0;
        *reinterpret_cast<uint4*>(&sh_key[b8 + 4]) = k1;
        *reinterpret_cast<uint4*>(&sh_idx[b8])     = iv;
    }
    __syncthreads();

    for (int k = 16; k <= NSORT; k <<= 1) {
        for (int j = k >> 1; j >= 8; j >>= 1) {
            for (int p = tid; p < (NSORT >> 1); p += BLOCK) {
                const int i   = ((p & ~(j - 1)) << 1) | (p & (j - 1));
                const int ixj = i | j;
                const unsigned int ka = sh_key[i], kb = sh_key[ixj];
                const unsigned short ia = sh_idx[i], ib = sh_idx[ixj];
                const bool gt = (ka > kb) || (ka == kb && ia > ib);
                const bool up = ((i & k) == 0);
                if (gt == up) {
                    sh_key[i] = kb; sh_key[ixj] = ka;
                    sh_idx[i] = ib; sh_idx[ixj] = ia;
                }
            }
            __syncthreads();
        }
        {
            const uint4 k0 = *reinterpret_cast<const uint4*>(&sh_key[b8]);
            const uint4 k1 = *reinterpret_cast<const uint4*>(&sh_key[b8 + 4]);
            const uint4 iv = *reinterpret_cast<const uint4*>(&sh_idx[b8]);
            K[0]=k0.x; K[1]=k0.y; K[2]=k0.z; K[3]=k0.w;
            K[4]=k1.x; K[5]=k1.y; K[6]=k1.z; K[7]=k1.w;
            I[0]=(unsigned short)(iv.x); I[1]=(unsigned short)(iv.x>>16);
            I[2]=(unsigned short)(iv.y); I[3]=(unsigned short)(iv.y>>16);
            I[4]=(unsigned short)(iv.z); I[5]=(unsigned short)(iv.z>>16);
            I[6]=(unsigned short)(iv.w); I[7]=(unsigned short)(iv.w>>16);
            const bool u8 = ((b8 & k) == 0);
            cswap(K[0],I[0],K[4],I[4], u8); cswap(K[1],I[1],K[5],I[5], u8);
            cswap(K[2],I[2],K[6],I[6], u8); cswap(K[3],I[3],K[7],I[7], u8);
            cswap(K[0],I[0],K[2],I[2], u8); cswap(K[1],I[1],K[3],I[3], u8);
            cswap(K[4],I[4],K[6],I[6], u8); cswap(K[5],I[5],K[7],I[7], u8);
            cswap(K[0],I[0],K[1],I[1], u8); cswap(K[2],I[2],K[3],I[3], u8);
            cswap(K[4],I[4],K[5],I[5], u8); cswap(K[6],I[6],K[7],I[7], u8);
            uint4 o0, o1, ov;
            o0.x=K[0]; o0.y=K[1]; o0.z=K[2]; o0.w=K[3];
            o1.x=K[4]; o1.y=K[5]; o1.z=K[6]; o1.w=K[7];
            ov.x=(unsigned int)I[0] | ((unsigned int)I[1]<<16);
            ov.y=(unsigned int)I[2] | ((unsigned int)I[3]<<16);
            ov.z=(unsigned int)I[4] | ((unsigned int)I[5]<<16);
            ov.w=(unsigned int)I[6] | ((unsigned int)I[7]<<16);
            *reinterpret_cast<uint4*>(&sh_key[b8])     = o0;
            *reinterpret_cast<uint4*>(&sh_key[b8 + 4]) = o1;
            *reinterpret_cast<uint4*>(&sh_idx[b8])     = ov;
        }
        __syncthreads();
    }

    for (int e = tid; e < NE; e += BLOCK) sh_key[e] = 0u;
    __syncthreads();

    if (tid < 64) {
        if (mode == 0)      kruskal_run<0>(sh_parent, sh_szto, sh_cnt64, sh_key, sh_idx, sign, tid);
        else if (mode == 1) kruskal_run<1>(sh_parent, sh_szto, sh_cnt64, sh_key, sh_idx, sign, tid);
        else                kruskal_run<2>(sh_parent, sh_szto, sh_cnt64, sh_key, sh_idx, sign, tid);
    }
    __syncthreads();

    {
        float part = 0.0f;
        for (int e = tid; e < NE; e += BLOCK) part += __uint_as_float(sh_key[e]);
        for (int off = 32; off > 0; off >>= 1) part += __shfl_down(part, off, 64);
        if ((tid & 63) == 0) sh_red[tid >> 6] = (double)part;
        __syncthreads();
        if (tid == 0) sh_sn = (float)(sh_red[0] + sh_red[1] + sh_red[2] + sh_red[3]);
        __syncthreads();
    }
    const float sn = sh_sn;

    double acc = 0.0;
    for (int pix = tid; pix < NNODE; pix += BLOCK) {
        const int r = pix >> 5, c = pix & 31;
        float nw = 0.0f;
        if (c < 31) { const int e = r * 31 + c;
            float v = __uint_as_float(sh_key[e]); if (sn > 0.0f) v = v / sn;
            const float g = sh_t[pix] + sh_t[pix + 1];
            if (sign == 0) { if (g >= 3.0f) v = 0.0f; } else { if (g < 10.0f) v = 0.0f; }
            nw += v; }
        if (c > 0)  { const int e = r * 31 + c - 1;
            float v = __uint_as_float(sh_key[e]); if (sn > 0.0f) v = v / sn;
            const float g = sh_t[pix - 1] + sh_t[pix];
            if (sign == 0) { if (g >= 3.0f) v = 0.0f; } else { if (g < 10.0f) v = 0.0f; }
            nw += v; }
        if (r < 31) { const int e = NH + pix;
            float v = __uint_as_float(sh_key[e]); if (sn > 0.0f) v = v / sn;
            const float g = sh_t[pix] + sh_t[pix + 32];
            if (sign == 0) { if (g >= 3.0f) v = 0.0f; } else { if (g < 10.0f) v = 0.0f; }
            nw += v; }
        if (r > 0)  { const int e = NH + pix - 32;
            float v = __uint_as_float(sh_key[e]); if (sn > 0.0f) v = v / sn;
            const float g = sh_t[pix - 32] + sh_t[pix];
            if (sign == 0) { if (g >= 3.0f) v = 0.0f; } else { if (g < 10.0f) v = 0.0f; }
            nw += v; }
        const float p = sh_p[pix];
        float term;
        if (sign == 0) term = (p * p) * nw;
        else { const float d = 20.0f - p; term = (0.1f * (d * d)) * nw; }
        acc += (double)term;
    }
    for (int off = 32; off > 0; off >>= 1) acc += __shfl_down(acc, off, 64);
    if ((tid & 63) == 0) sh_red[tid >> 6] = acc;
    __syncthreads();
    if (tid == 0)
        atomicAdd(&acc_ws[1], sh_red[0] + sh_red[1] + sh_red[2] + sh_red[3]);

    } // !skip_all
}

__global__ __launch_bounds__(BLOCK) void mse_kernel(const float* __restrict__ pred,
                                                    const float* __restrict__ tgt,
                                                    double* __restrict__ acc_ws,
                                                    long n) {
    double acc = 0.0;
    for (long i = (long)blockIdx.x * BLOCK + threadIdx.x; i < n; i += (long)gridDim.x * BLOCK) {
        const float d = pred[i] - tgt[i];
        acc += (double)(d * d);
    }
    for (int off = 32; off > 0; off >>= 1) acc += __shfl_down(acc, off, 64);
    __shared__ double red[4];
    if ((threadIdx.x & 63) == 0) red[threadIdx.x >> 6] = acc;
    __syncthreads();
    if (threadIdx.x == 0)
        atomicAdd(&acc_ws[0], red[0] + red[1] + red[2] + red[3]);
}

__global__ void fin_kernel(const double* __restrict__ acc_ws, float* __restrict__ out, long n) {
    if (threadIdx.x == 0 && blockIdx.x == 0) {
        out[0] = (float)(acc_ws[0] / (double)n);
        out[1] = (float)(acc_ws[1] * (double)1e-4f);
    }
}

extern "C" void kernel_launch(void* const* d_in, const int* in_sizes, int n_in,
                              void* d_out, int out_size, void* d_ws, size_t ws_size,
                              hipStream_t stream) {
    const float* pred = (const float*)d_in[0];
    const float* tgt  = (const float*)d_in[1];
    float* out = (float*)d_out;
    double* acc = (double*)d_ws;

    const long n = (long)in_sizes[0];            // 4*1*128*128*128 = 8388608
    const int  B = (int)(n / 2097152);           // batches
    const int  NW = 96 * B;                      // prep work items
    const size_t need = 64 + (size_t)NW * NNODE * 9 + (size_t)NW * 4;

    hipMemsetAsync(d_ws, 0, 2 * sizeof(double), stream);
    if (ws_size >= need) {
        prep_kernel<<<NW, BLOCK, 0, stream>>>(pred, tgt, (char*)d_ws, acc, B);
        solve_kernel<<<192 * B, BLOCK, 0, stream>>>((const char*)d_ws, acc, B);
    } else {
        mse_kernel<<<1024, BLOCK, 0, stream>>>(pred, tgt, acc, n);
        conn_kernel<<<192 * B, BLOCK, 0, stream>>>(pred, tgt, acc, B);
    }
    fin_kernel<<<1, 64, 0, stream>>>(acc, out, n);
}

// Round 16
// 456.721 us; speedup vs baseline: 1.3642x; 1.0779x over previous
//
#include <hip/hip_runtime.h>

#define BLOCK 256
#define NNODE 1024
#define NH    992
#define NE    1984
#define NSORT 2048
#define LMAX  12
#define CHUNK 64
#define NPASS (NE / CHUNK)

typedef unsigned long long ull;

__device__ __forceinline__ void edge_nodes(int e, int& a, int& b) {
    if (e < NH) {                 // horizontal: (r,c)-(r,c+1), e = r*31+c
        int r = e / 31;
        int c = e - r * 31;
        a = (r << 5) + c;
        b = a + 1;
    } else {                      // vertical: (r,c)-(r+1,c), e-992 = r*32+c
        a = e - NH;
        b = a + 32;
    }
}

__device__ __forceinline__ int find_par(unsigned short* par, int x) {
    volatile unsigned short* vp = par;
    int r = x;
    int p = vp[r];
    while (p != r) { r = p; p = vp[r]; }
    int c = x;
    while (c != r) { const int nxt = vp[c]; vp[c] = (unsigned short)r; c = nxt; }
    return r;
}

__device__ __forceinline__ int dot16x4(ull a, ull b) {
    int s  = (int)(a & 0xFFFFu)         * (int)(b & 0xFFFFu);
    s     += (int)((a >> 16) & 0xFFFFu) * (int)((b >> 16) & 0xFFFFu);
    s     += (int)((a >> 32) & 0xFFFFu) * (int)((b >> 32) & 0xFFFFu);
    s     += (int)((a >> 48) & 0xFFFFu) * (int)((b >> 48) & 0xFFFFu);
    return s;
}

__device__ __forceinline__ void cswap(unsigned int& ka, unsigned short& ia,
                                      unsigned int& kb, unsigned short& ib, bool up) {
    const bool gt = (ka > kb) || (ka == kb && ia > ib);
    if (gt == up) {
        const unsigned int  tk = ka; ka = kb; kb = tk;
        const unsigned short ti = ia; ia = ib; ib = ti;
    }
}

// ----------------------------------------------------------------------------
// Hybrid Kruskal (wave 0) — r13 configuration (measured best).
// Per 64-edge pass (MODE<=1):
//  (a) ONE claim round: candidate lanes atomicMax both roots with tag
//      ((pass+1)<<6)|(63-lane): max tag == MIN lane; tags monotone over passes
//      so stale tags always lose -> no reset needed.
//  (b) winners (own both claims) == greedy prefix-independent set: no smaller
//      candidate shares their roots -> they see the exact serial-prefix state
//      and are mutually disjoint -> commit IN PARALLEL per-lane.
//  (c) losers re-find (winners' parents visible: same-wave DS order + drain)
//      and run the serial loop (shfl pack, wave-uniform state loads,
//      register-maintained roots). NOTE: shfl (ds_bpermute) pipelines with
//      the following LDS state loads; readlane variants measured SLOWER
//      (r14: +175us, r15: +33us) — do not "optimize" this.
// Claims alias unused sh_cnt64 words: MODE 0 -> u32[node]; MODE 1 -> u32 at
// node*6+2 (low half of unused word-1). MODE 2 (L>=5, rare) is pure serial.
// ----------------------------------------------------------------------------
template<int MODE>
__device__ __forceinline__ void kruskal_run(unsigned short* sh_parent,
                                            unsigned int*   sh_szto,
                                            ull*            sh_cnt64,
                                            unsigned int*   sh_key,
                                            const unsigned short* sh_idx,
                                            const int sign, const int lane) {
    unsigned int* claim32 = (unsigned int*)sh_cnt64;
    for (int pass = 0; pass < NPASS; ++pass) {
        const int e = sh_idx[pass * CHUNK + lane];
        int a, bb; edge_nodes(e, a, bb);
        int ra = find_par(sh_parent, a);
        int rb = find_par(sh_parent, bb);
        bool cand = (ra != rb);

        if (MODE <= 1) {
            const unsigned int tag = ((unsigned int)(pass + 1) << 6) | (unsigned int)(63 - lane);
            const int ia = (MODE == 0) ? ra : (ra * 6 + 2);
            const int ib = (MODE == 0) ? rb : (rb * 6 + 2);
            if (cand) {
                atomicMax(&claim32[ia], tag);
                atomicMax(&claim32[ib], tag);
            }
            asm volatile("s_waitcnt lgkmcnt(0)" ::: "memory");
            __builtin_amdgcn_sched_barrier(0);
            bool win = false;
            if (cand) win = (claim32[ia] == tag) && (claim32[ib] == tag);
            if (win) {
                // parallel commit: winners' root pairs are mutually disjoint
                const unsigned int xa = sh_szto[ra], xb = sh_szto[rb];
                const int ta = (int)(xa >> 16), tb = (int)(xb >> 16);
                int wv;
                ull a0 = 0, b0 = 0;
                if (MODE == 0) {
                    wv = ta * tb;                 // L==1: same == ta*tb
                } else {
                    a0 = sh_cnt64[ra * 3]; b0 = sh_cnt64[rb * 3];
                    const int same = dot16x4(a0, b0);
                    wv = sign ? same : (ta * tb - same);
                }
                const int big = ((xa & 0xFFFFu) > (xb & 0xFFFFu));
                const int rs = big ? ra : rb;     // survivor (union by size)
                const int rl = big ? rb : ra;
                sh_key[e] = __float_as_uint((float)wv);
                sh_szto[rs] = xa + xb;            // sums <= 2048: no field carry
                if (MODE == 1) sh_cnt64[rs * 3] = a0 + b0;  // per-lane sums <= 1024
                sh_parent[rl] = (unsigned short)rs;
                cand = false;                     // handled
            }
            asm volatile("s_waitcnt lgkmcnt(0)" ::: "memory");
            __builtin_amdgcn_sched_barrier(0);
            if (cand) {                           // tail: re-find post-winners
                ra = find_par(sh_parent, ra);
                rb = find_par(sh_parent, rb);
                cand = (ra != rb);
            }
        }

        // ---- serial tail (shfl pack, wave-uniform state loads) ----
        ull m = __ballot(cand);
        while (m) {
            const int i = (int)__builtin_ctzll(m);
            m &= m - 1;
            const unsigned int pack = (unsigned int)ra | ((unsigned int)rb << 10) | ((unsigned int)e << 20);
            const unsigned int pk = (unsigned int)__shfl((int)pack, i);
            const int ra_i = (int)(pk & 1023u);
            const int rb_i = (int)((pk >> 10) & 1023u);
            if (ra_i == rb_i) continue;           // became a cycle mid-pass
            const int se = (int)(pk >> 20);
            const unsigned int xa = sh_szto[ra_i], xb = sh_szto[rb_i];
            const int ta = (int)(xa >> 16), tb = (int)(xb >> 16);
            const int big = ((xa & 0xFFFFu) > (xb & 0xFFFFu));
            const int rs = big ? ra_i : rb_i;
            const int rl = big ? rb_i : ra_i;
            int wv;
            if (MODE == 0) {
                wv = ta * tb;
            } else if (MODE == 1) {
                const ull a0 = sh_cnt64[ra_i * 3];
                const ull b0 = sh_cnt64[rb_i * 3];
                const int same = dot16x4(a0, b0);
                wv = sign ? same : (ta * tb - same);
                if (lane == 0 && (ta + tb) > 0)
                    sh_cnt64[rs * 3] = a0 + b0;
            } else {
                const ull a0 = sh_cnt64[ra_i * 3 + 0];
                const ull a1 = sh_cnt64[ra_i * 3 + 1];
                const ull a2 = sh_cnt64[ra_i * 3 + 2];
                const ull b0 = sh_cnt64[rb_i * 3 + 0];
                const ull b1 = sh_cnt64[rb_i * 3 + 1];
                const ull b2 = sh_cnt64[rb_i * 3 + 2];
                const int same = dot16x4(a0, b0) + dot16x4(a1, b1) + dot16x4(a2, b2);
                wv = sign ? same : (ta * tb - same);
                if (lane == 0 && (ta + tb) > 0) {
                    sh_cnt64[rs * 3 + 0] = a0 + b0;
                    sh_cnt64[rs * 3 + 1] = a1 + b1;
                    sh_cnt64[rs * 3 + 2] = a2 + b2;
                }
            }
            if (lane == 0) {
                sh_key[se] = __float_as_uint((float)wv);
                sh_szto[rs] = xa + xb;
                sh_parent[rl] = (unsigned short)rs;
            }
            if (ra == rl) ra = rs;
            if (rb == rl) rb = rs;
        }
    }
}

// shared UF init (claims zeroed in the aliased words)
template<int MODE>
__device__ __forceinline__ void uf_init(unsigned short* sh_parent,
                                        unsigned int* sh_szto,
                                        ull* sh_cnt64,
                                        const unsigned char* sh_seg,
                                        const int tid) {
    unsigned int* claim32 = (unsigned int*)sh_cnt64;
    for (int pix = tid; pix < NNODE; pix += BLOCK) {
        sh_parent[pix] = (unsigned short)pix;
        const int s = sh_seg[pix];
        const unsigned int tot = (s > 0 && s <= LMAX) ? 1u : 0u;
        sh_szto[pix] = 1u | (tot << 16);
        if (MODE == 0) {
            claim32[pix] = 0u;                    // claim array
        } else {
            ull c0 = 0, c1 = 0, c2 = 0;
            if (s >= 1 && s <= LMAX) {
                const ull bit = 1ull << (((s - 1) & 3) * 16);
                const int q = (s - 1) >> 2;
                if (q == 0) c0 = bit; else if (q == 1) c1 = bit; else c2 = bit;
            }
            sh_cnt64[pix * 3 + 0] = c0;
            sh_cnt64[pix * 3 + 1] = (MODE == 1) ? 0ull : c1;   // mode1: claim word
            if (MODE == 2) sh_cnt64[pix * 3 + 2] = c2;
        }
    }
}

// ============================================================================
// prep_kernel: one block per (item, win, b). Projection + dilate + CC + label.
// axis_id==2 blocks additionally accumulate the MSE (each voxel exactly once).
// ============================================================================
__global__ __launch_bounds__(BLOCK) void prep_kernel(const float* __restrict__ pred,
                                                     const float* __restrict__ tgt,
                                                     char* __restrict__ ws,
                                                     double* __restrict__ acc_ws,
                                                     int B) {
    __shared__ alignas(16) float sh_p[NNODE];
    __shared__ alignas(16) float sh_t[NNODE];
    __shared__ unsigned char  mA[NNODE];
    __shared__ unsigned char  mB[NNODE];
    __shared__ unsigned short sh_parent[NNODE];
    __shared__ unsigned short sh_lab[NNODE];
    __shared__ int sh_L;
    __shared__ double sh_redp[4];

    const int tid = threadIdx.x;
    const int w = blockIdx.x;                         // work index
    int wg = w;
    const int b    = wg % B;  wg /= B;
    const int win  = wg & 3;  wg >>= 2;
    const int item = wg;                              // 0..23
    const int axis_id = item % 3;
    const int cube = item / 3;
    const int ci = cube & 1;
    const int cj = (cube >> 1) & 1;
    const int ck = (cube >> 2) & 1;
    const int wk = win >> 1;
    const int wj = win & 1;

    const int NW = 96 * B;
    float* Pb = (float*)(ws + 64);
    float* Tb = Pb + (size_t)NW * NNODE;
    unsigned char* Sb = (unsigned char*)(Tb + (size_t)NW * NNODE);
    int* Lb = (int*)(Sb + (size_t)NW * NNODE);

    const size_t base = (size_t)b * 2097152u;

    // ---- projection mins (32x32 window of the 64x64 projection) ----
    if (axis_id == 2) {
        // contiguous along the reduced axis: float4 loads; also accumulate MSE
        double msum = 0.0;
        for (int pix = tid; pix < NNODE; pix += BLOCK) {
            const int r = pix >> 5, c = pix & 31;
            const int R = wk * 32 + r, C = wj * 32 + c;
            const size_t idx0 = base + (size_t)(ck * 64 + R) * 16384u + (size_t)(cj * 64 + C) * 128u + (size_t)(ci * 64);
            const float4* pp = reinterpret_cast<const float4*>(pred + idx0);
            const float4* tp = reinterpret_cast<const float4*>(tgt + idx0);
            float pm = 3.4e38f, tm = 3.4e38f;
            #pragma unroll
            for (int h = 0; h < 16; ++h) {
                const float4 a = pp[h];
                const float4 t = tp[h];
                pm = fminf(pm, fminf(fminf(a.x, a.y), fminf(a.z, a.w)));
                tm = fminf(tm, fminf(fminf(t.x, t.y), fminf(t.z, t.w)));
                const float dx = a.x - t.x, dy = a.y - t.y;
                const float dz = a.z - t.z, dw = a.w - t.w;
                msum += (double)(dx * dx);
                msum += (double)(dy * dy);
                msum += (double)(dz * dz);
                msum += (double)(dw * dw);
            }
            sh_p[pix] = pm;
            sh_t[pix] = tm;
        }
        for (int off = 32; off > 0; off >>= 1) msum += __shfl_down(msum, off, 64);
        if ((tid & 63) == 0) sh_redp[tid >> 6] = msum;
        __syncthreads();
        if (tid == 0)
            atomicAdd(&acc_ws[0], sh_redp[0] + sh_redp[1] + sh_redp[2] + sh_redp[3]);
    } else {
        const int r  = tid >> 3;
        const int c0 = (tid & 7) << 2;
        const int R = wk * 32 + r, C = wj * 32 + c0;
        size_t idx0; int hstride;
        if (axis_id == 0) {
            idx0 = base + (size_t)(ck * 64) * 16384u + (size_t)(cj * 64 + R) * 128u + (size_t)(ci * 64 + C);
            hstride = 16384;
        } else {
            idx0 = base + (size_t)(ck * 64 + R) * 16384u + (size_t)(cj * 64) * 128u + (size_t)(ci * 64 + C);
            hstride = 128;
        }
        float4 pm = make_float4(3.4e38f, 3.4e38f, 3.4e38f, 3.4e38f);
        float4 tm = pm;
        #pragma unroll 8
        for (int h = 0; h < 64; ++h) {
            const float4 a  = *reinterpret_cast<const float4*>(pred + idx0);
            const float4 t4 = *reinterpret_cast<const float4*>(tgt + idx0);
            pm.x = fminf(pm.x, a.x);  pm.y = fminf(pm.y, a.y);
            pm.z = fminf(pm.z, a.z);  pm.w = fminf(pm.w, a.w);
            tm.x = fminf(tm.x, t4.x); tm.y = fminf(tm.y, t4.y);
            tm.z = fminf(tm.z, t4.z); tm.w = fminf(tm.w, t4.w);
            idx0 += (size_t)hstride;
        }
        *reinterpret_cast<float4*>(&sh_p[(r << 5) + c0]) = pm;
        *reinterpret_cast<float4*>(&sh_t[(r << 5) + c0]) = tm;
        __syncthreads();
    }

    // ---- dilate5 of (t == 0), von Neumann, zero padded, window-local ----
    for (int pix = tid; pix < NNODE; pix += BLOCK)
        mA[pix] = (sh_t[pix] == 0.0f) ? 1 : 0;
    __syncthreads();
    for (int it = 0; it < 5; ++it) {
        unsigned char* src = (it & 1) ? mB : mA;
        unsigned char* dst = (it & 1) ? mA : mB;
        for (int pix = tid; pix < NNODE; pix += BLOCK) {
            const int r = pix >> 5, c = pix & 31;
            unsigned char v = src[pix];
            if (r > 0)  v |= src[pix - 32];
            if (r < 31) v |= src[pix + 32];
            if (c > 0)  v |= src[pix - 1];
            if (c < 31) v |= src[pix + 1];
            dst[pix] = v;
        }
        __syncthreads();
    }
    for (int pix = tid; pix < NNODE; pix += BLOCK)
        mA[pix] = mB[pix] ^ 1;                        // fg
    __syncthreads();

    // ---- 8-connected CC labeling on fg via min-index propagation ----
    // single barrier per iteration via __syncthreads_or
    for (int pix = tid; pix < NNODE; pix += BLOCK)
        sh_parent[pix] = mA[pix] ? (unsigned short)pix : (unsigned short)0xFFFF;
    __syncthreads();
    for (;;) {
        int changed = 0;
        for (int pix = tid; pix < NNODE; pix += BLOCK) {
            if (!mA[pix]) continue;
            const int r = pix >> 5, c = pix & 31;
            int m = sh_parent[pix];
            #pragma unroll
            for (int d = 0; d < 8; ++d) {
                static const int dr[8] = {-1,-1,-1, 0, 0, 1, 1, 1};
                static const int dc[8] = {-1, 0, 1,-1, 1,-1, 0, 1};
                const int rr = r + dr[d], cc = c + dc[d];
                if (rr < 0 || rr > 31 || cc < 0 || cc > 31) continue;
                const int nb = (rr << 5) + cc;
                if (mA[nb]) { int v = sh_parent[nb]; if (v < m) m = v; }
            }
            while ((int)sh_parent[m] < m) m = sh_parent[m];
            if (m < (int)sh_parent[pix]) { sh_parent[pix] = (unsigned short)m; changed = 1; }
        }
        if (!__syncthreads_or(changed)) break;
    }

    // ---- compact labels ----
    if (tid == 0) sh_L = 0;
    __syncthreads();
    for (int pix = tid; pix < NNODE; pix += BLOCK) {
        if (mA[pix] && (int)sh_parent[pix] == pix) {
            const int id = atomicAdd(&sh_L, 1);
            sh_lab[pix] = (unsigned short)(id + 1);
        }
    }
    __syncthreads();

    // ---- write P, T, SEG, L to workspace (coalesced) ----
    {
        const int p4 = tid << 2;                      // exactly one float4 per thread
        *reinterpret_cast<float4*>(&Pb[(size_t)w * NNODE + p4]) =
            *reinterpret_cast<const float4*>(&sh_p[p4]);
        *reinterpret_cast<float4*>(&Tb[(size_t)w * NNODE + p4]) =
            *reinterpret_cast<const float4*>(&sh_t[p4]);
        unsigned int packed = 0;
        #pragma unroll
        for (int q = 0; q < 4; ++q) {
            const int pix = p4 + q;
            unsigned int s = 0;
            if (mA[pix]) {
                int lab = sh_lab[sh_parent[pix]];
                if (lab > 255) lab = 255;
                s = (unsigned int)lab;
            }
            packed |= s << (q * 8);
        }
        ((unsigned int*)Sb)[(size_t)w * (NNODE / 4) + tid] = packed;
        if (tid == 0) Lb[w] = sh_L;
    }
}

// ============================================================================
// solve_kernel: one block per (sign, item, win, b). Reads P/T/SEG/L; skips
// exact-zero blocks instantly; key-build + sort + hybrid Kruskal + gather.
// ============================================================================
__global__ __launch_bounds__(BLOCK) void solve_kernel(const char* __restrict__ ws_c,
                                                      double* __restrict__ acc_ws,
                                                      int B) {
    __shared__ alignas(16) float          sh_p[NNODE];
    __shared__ alignas(16) float          sh_t[NNODE];
    __shared__ alignas(16) unsigned int   sh_key[NSORT];
    __shared__ alignas(16) unsigned short sh_idx[NSORT];
    __shared__ unsigned short sh_parent[NNODE];
    __shared__ unsigned int   sh_szto[NNODE];
    __shared__ ull            sh_cnt64[NNODE * 3];
    __shared__ alignas(16) unsigned char sh_seg[NNODE];
    __shared__ float          sh_sn;
    __shared__ double         sh_red[4];

    const int tid = threadIdx.x;
    int wg = blockIdx.x;
    const int sign = wg & 1;  wg >>= 1;
    const int w = wg;                                  // work index 0..96B-1

    const int NW = 96 * B;
    const float* Pb = (const float*)(ws_c + 64);
    const float* Tb = Pb + (size_t)NW * NNODE;
    const unsigned char* Sb = (const unsigned char*)(Tb + (size_t)NW * NNODE);
    const int* Lb = (const int*)(Sb + (size_t)NW * NNODE);

    // ---- skip check before touching LDS ----
    const int Lraw = Lb[w];
    if (Lraw == 0 || (Lraw == 1 && sign == 0)) return;   // exact-zero contribution
    const int mode = (Lraw <= 1) ? 0 : ((Lraw <= 4) ? 1 : 2);

    // ---- load P/T/SEG (one float4 / u32 per thread) ----
    {
        const int p4 = tid << 2;
        *reinterpret_cast<float4*>(&sh_p[p4]) =
            *reinterpret_cast<const float4*>(&Pb[(size_t)w * NNODE + p4]);
        *reinterpret_cast<float4*>(&sh_t[p4]) =
            *reinterpret_cast<const float4*>(&Tb[(size_t)w * NNODE + p4]);
        ((unsigned int*)sh_seg)[tid] =
            ((const unsigned int*)Sb)[(size_t)w * (NNODE / 4) + tid];
    }
    __syncthreads();

    // ---- union-find init (incl. claim zeroing) ----
    if (mode == 0)      uf_init<0>(sh_parent, sh_szto, sh_cnt64, sh_seg, tid);
    else if (mode == 1) uf_init<1>(sh_parent, sh_szto, sh_cnt64, sh_seg, tid);
    else                uf_init<2>(sh_parent, sh_szto, sh_cnt64, sh_seg, tid);
    __syncthreads();

    // ---- build sort keys in registers + k=2,4,8 rounds before first store ----
    unsigned int   K[8];
    unsigned short I[8];
    const int b8 = tid << 3;
    #pragma unroll
    for (int l = 0; l < 8; ++l) {
        const int e = b8 + l;
        if (e < NE) {
            int a, bb; edge_nodes(e, a, bb);
            float cost = sh_p[a] + sh_p[bb];
            const float g = sh_t[a] + sh_t[bb];
            if (sign == 0) { if (g > 10.0f) cost = 10.0f; }
            else           { if (g <  3.0f) cost = 0.0f;  }
            K[l] = ~__float_as_uint(cost);
            I[l] = (unsigned short)e;
        } else {
            K[l] = 0xFFFFFFFFu;
            I[l] = (unsigned short)0xFFFF;
        }
    }
    cswap(K[0],I[0],K[1],I[1], true );
    cswap(K[2],I[2],K[3],I[3], false);
    cswap(K[4],I[4],K[5],I[5], true );
    cswap(K[6],I[6],K[7],I[7], false);
    cswap(K[0],I[0],K[2],I[2], true );
    cswap(K[1],I[1],K[3],I[3], true );
    cswap(K[4],I[4],K[6],I[6], false);
    cswap(K[5],I[5],K[7],I[7], false);
    cswap(K[0],I[0],K[1],I[1], true );
    cswap(K[2],I[2],K[3],I[3], true );
    cswap(K[4],I[4],K[5],I[5], false);
    cswap(K[6],I[6],K[7],I[7], false);
    {
        const bool u8 = ((b8 & 8) == 0);
        cswap(K[0],I[0],K[4],I[4], u8); cswap(K[1],I[1],K[5],I[5], u8);
        cswap(K[2],I[2],K[6],I[6], u8); cswap(K[3],I[3],K[7],I[7], u8);
        cswap(K[0],I[0],K[2],I[2], u8); cswap(K[1],I[1],K[3],I[3], u8);
        cswap(K[4],I[4],K[6],I[6], u8); cswap(K[5],I[5],K[7],I[7], u8);
        cswap(K[0],I[0],K[1],I[1], u8); cswap(K[2],I[2],K[3],I[3], u8);
        cswap(K[4],I[4],K[5],I[5], u8); cswap(K[6],I[6],K[7],I[7], u8);
    }
    {
        uint4 k0, k1, iv;
        k0.x=K[0]; k0.y=K[1]; k0.z=K[2]; k0.w=K[3];
        k1.x=K[4]; k1.y=K[5]; k1.z=K[6]; k1.w=K[7];
        iv.x=(unsigned int)I[0] | ((unsigned int)I[1]<<16);
        iv.y=(unsigned int)I[2] | ((unsigned int)I[3]<<16);
        iv.z=(unsigned int)I[4] | ((unsigned int)I[5]<<16);
        iv.w=(unsigned int)I[6] | ((unsigned int)I[7]<<16);
        *reinterpret_cast<uint4*>(&sh_key[b8])     = k0;
        *reinterpret_cast<uint4*>(&sh_key[b8 + 4]) = k1;
        *reinterpret_cast<uint4*>(&sh_idx[b8])     = iv;
    }
    __syncthreads();

    // ---- bitonic k=16..2048: j>=8 via LDS pair-indexed, j=4,2,1 in registers ----
    for (int k = 16; k <= NSORT; k <<= 1) {
        for (int j = k >> 1; j >= 8; j >>= 1) {
            for (int p = tid; p < (NSORT >> 1); p += BLOCK) {
                const int i   = ((p & ~(j - 1)) << 1) | (p & (j - 1));
                const int ixj = i | j;
                const unsigned int ka = sh_key[i], kb = sh_key[ixj];
                const unsigned short ia = sh_idx[i], ib = sh_idx[ixj];
                const bool gt = (ka > kb) || (ka == kb && ia > ib);
                const bool up = ((i & k) == 0);
                if (gt == up) {
                    sh_key[i] = kb; sh_key[ixj] = ka;
                    sh_idx[i] = ib; sh_idx[ixj] = ia;
                }
            }
            __syncthreads();
        }
        {
            const uint4 k0 = *reinterpret_cast<const uint4*>(&sh_key[b8]);
            const uint4 k1 = *reinterpret_cast<const uint4*>(&sh_key[b8 + 4]);
            const uint4 iv = *reinterpret_cast<const uint4*>(&sh_idx[b8]);
            K[0]=k0.x; K[1]=k0.y; K[2]=k0.z; K[3]=k0.w;
            K[4]=k1.x; K[5]=k1.y; K[6]=k1.z; K[7]=k1.w;
            I[0]=(unsigned short)(iv.x); I[1]=(unsigned short)(iv.x>>16);
            I[2]=(unsigned short)(iv.y); I[3]=(unsigned short)(iv.y>>16);
            I[4]=(unsigned short)(iv.z); I[5]=(unsigned short)(iv.z>>16);
            I[6]=(unsigned short)(iv.w); I[7]=(unsigned short)(iv.w>>16);
            const bool u8 = ((b8 & k) == 0);
            cswap(K[0],I[0],K[4],I[4], u8); cswap(K[1],I[1],K[5],I[5], u8);
            cswap(K[2],I[2],K[6],I[6], u8); cswap(K[3],I[3],K[7],I[7], u8);
            cswap(K[0],I[0],K[2],I[2], u8); cswap(K[1],I[1],K[3],I[3], u8);
            cswap(K[4],I[4],K[6],I[6], u8); cswap(K[5],I[5],K[7],I[7], u8);
            cswap(K[0],I[0],K[1],I[1], u8); cswap(K[2],I[2],K[3],I[3], u8);
            cswap(K[4],I[4],K[5],I[5], u8); cswap(K[6],I[6],K[7],I[7], u8);
            uint4 o0, o1, ov;
            o0.x=K[0]; o0.y=K[1]; o0.z=K[2]; o0.w=K[3];
            o1.x=K[4]; o1.y=K[5]; o1.z=K[6]; o1.w=K[7];
            ov.x=(unsigned int)I[0] | ((unsigned int)I[1]<<16);
            ov.y=(unsigned int)I[2] | ((unsigned int)I[3]<<16);
            ov.z=(unsigned int)I[4] | ((unsigned int)I[5]<<16);
            ov.w=(unsigned int)I[6] | ((unsigned int)I[7]<<16);
            *reinterpret_cast<uint4*>(&sh_key[b8])     = o0;
            *reinterpret_cast<uint4*>(&sh_key[b8 + 4]) = o1;
            *reinterpret_cast<uint4*>(&sh_idx[b8])     = ov;
        }
        __syncthreads();
    }

    // ---- zero edge weights ----
    for (int e = tid; e < NE; e += BLOCK) sh_key[e] = 0u;
    __syncthreads();

    // ---- single-wave hybrid Kruskal (wave 0) ----
    if (tid < 64) {
        if (mode == 0)      kruskal_run<0>(sh_parent, sh_szto, sh_cnt64, sh_key, sh_idx, sign, tid);
        else if (mode == 1) kruskal_run<1>(sh_parent, sh_szto, sh_cnt64, sh_key, sh_idx, sign, tid);
        else                kruskal_run<2>(sh_parent, sh_szto, sh_cnt64, sh_key, sh_idx, sign, tid);
    }
    __syncthreads();

    // ---- normalization sum ----
    {
        float part = 0.0f;
        for (int e = tid; e < NE; e += BLOCK) part += __uint_as_float(sh_key[e]);
        for (int off = 32; off > 0; off >>= 1) part += __shfl_down(part, off, 64);
        if ((tid & 63) == 0) sh_red[tid >> 6] = (double)part;
        __syncthreads();
        if (tid == 0) sh_sn = (float)(sh_red[0] + sh_red[1] + sh_red[2] + sh_red[3]);
        __syncthreads();
    }
    const float sn = sh_sn;

    // ---- per-node gather + conn contribution ----
    double acc = 0.0;
    for (int pix = tid; pix < NNODE; pix += BLOCK) {
        const int r = pix >> 5, c = pix & 31;
        float nw = 0.0f;
        if (c < 31) { const int e = r * 31 + c;
            float v = __uint_as_float(sh_key[e]); if (sn > 0.0f) v = v / sn;
            const float g = sh_t[pix] + sh_t[pix + 1];
            if (sign == 0) { if (g >= 3.0f) v = 0.0f; } else { if (g < 10.0f) v = 0.0f; }
            nw += v; }
        if (c > 0)  { const int e = r * 31 + c - 1;
            float v = __uint_as_float(sh_key[e]); if (sn > 0.0f) v = v / sn;
            const float g = sh_t[pix - 1] + sh_t[pix];
            if (sign == 0) { if (g >= 3.0f) v = 0.0f; } else { if (g < 10.0f) v = 0.0f; }
            nw += v; }
        if (r < 31) { const int e = NH + pix;
            float v = __uint_as_float(sh_key[e]); if (sn > 0.0f) v = v / sn;
            const float g = sh_t[pix] + sh_t[pix + 32];
            if (sign == 0) { if (g >= 3.0f) v = 0.0f; } else { if (g < 10.0f) v = 0.0f; }
            nw += v; }
        if (r > 0)  { const int e = NH + pix - 32;
            float v = __uint_as_float(sh_key[e]); if (sn > 0.0f) v = v / sn;
            const float g = sh_t[pix - 32] + sh_t[pix];
            if (sign == 0) { if (g >= 3.0f) v = 0.0f; } else { if (g < 10.0f) v = 0.0f; }
            nw += v; }
        const float p = sh_p[pix];
        float term;
        if (sign == 0) term = (p * p) * nw;
        else { const float d = 20.0f - p; term = (0.1f * (d * d)) * nw; }
        acc += (double)term;
    }
    for (int off = 32; off > 0; off >>= 1) acc += __shfl_down(acc, off, 64);
    if ((tid & 63) == 0) sh_red[tid >> 6] = acc;
    __syncthreads();
    if (tid == 0)
        atomicAdd(&acc_ws[1], sh_red[0] + sh_red[1] + sh_red[2] + sh_red[3]);
}

// ============================================================================
// Fallback fused kernel — used only if the workspace is too small.
// ============================================================================
__global__ __launch_bounds__(BLOCK) void conn_kernel(const float* __restrict__ pred,
                                                     const float* __restrict__ tgt,
                                                     double* __restrict__ acc_ws,
                                                     int B) {
    __shared__ alignas(16) float          sh_p[NNODE];
    __shared__ alignas(16) float          sh_t[NNODE];
    __shared__ alignas(16) unsigned int   sh_key[NSORT];
    __shared__ alignas(16) unsigned short sh_idx[NSORT];
    __shared__ unsigned short sh_parent[NNODE];
    __shared__ unsigned int   sh_szto[NNODE];
    __shared__ ull            sh_cnt64[NNODE * 3];
    __shared__ unsigned char  sh_seg[NNODE];
    __shared__ int            sh_L;
    __shared__ float          sh_sn;
    __shared__ double         sh_red[4];

    const int tid = threadIdx.x;
    int wg = blockIdx.x;
    const int sign = (wg >> 3) & 1;
    wg = (wg & 7) | ((wg >> 4) << 3);
    const int b    = wg % B;  wg /= B;
    const int win  = wg & 3;  wg >>= 2;
    const int item = wg;
    const int axis_id = item % 3;
    const int cube = item / 3;
    const int ci = cube & 1;
    const int cj = (cube >> 1) & 1;
    const int ck = (cube >> 2) & 1;
    const int wk = win >> 1;
    const int wj = win & 1;

    const size_t base = (size_t)b * 2097152u;

    if (axis_id == 2) {
        for (int pix = tid; pix < NNODE; pix += BLOCK) {
            const int r = pix >> 5, c = pix & 31;
            const int R = wk * 32 + r, C = wj * 32 + c;
            const size_t idx0 = base + (size_t)(ck * 64 + R) * 16384u + (size_t)(cj * 64 + C) * 128u + (size_t)(ci * 64);
            const float4* pp = reinterpret_cast<const float4*>(pred + idx0);
            const float4* tp = reinterpret_cast<const float4*>(tgt + idx0);
            float pm = 3.4e38f, tm = 3.4e38f;
            #pragma unroll
            for (int h = 0; h < 16; ++h) {
                const float4 a = pp[h];
                const float4 t = tp[h];
                pm = fminf(pm, fminf(fminf(a.x, a.y), fminf(a.z, a.w)));
                tm = fminf(tm, fminf(fminf(t.x, t.y), fminf(t.z, t.w)));
            }
            sh_p[pix] = pm;
            sh_t[pix] = tm;
        }
    } else {
        const int r  = tid >> 3;
        const int c0 = (tid & 7) << 2;
        const int R = wk * 32 + r, C = wj * 32 + c0;
        size_t idx0; int hstride;
        if (axis_id == 0) {
            idx0 = base + (size_t)(ck * 64) * 16384u + (size_t)(cj * 64 + R) * 128u + (size_t)(ci * 64 + C);
            hstride = 16384;
        } else {
            idx0 = base + (size_t)(ck * 64 + R) * 16384u + (size_t)(cj * 64) * 128u + (size_t)(ci * 64 + C);
            hstride = 128;
        }
        float4 pm = make_float4(3.4e38f, 3.4e38f, 3.4e38f, 3.4e38f);
        float4 tm = pm;
        #pragma unroll 8
        for (int h = 0; h < 64; ++h) {
            const float4 a  = *reinterpret_cast<const float4*>(pred + idx0);
            const float4 t4 = *reinterpret_cast<const float4*>(tgt + idx0);
            pm.x = fminf(pm.x, a.x);  pm.y = fminf(pm.y, a.y);
            pm.z = fminf(pm.z, a.z);  pm.w = fminf(pm.w, a.w);
            tm.x = fminf(tm.x, t4.x); tm.y = fminf(tm.y, t4.y);
            tm.z = fminf(tm.z, t4.z); tm.w = fminf(tm.w, t4.w);
            idx0 += (size_t)hstride;
        }
        *reinterpret_cast<float4*>(&sh_p[(r << 5) + c0]) = pm;
        *reinterpret_cast<float4*>(&sh_t[(r << 5) + c0]) = tm;
    }
    __syncthreads();

    unsigned char* mA = sh_seg;
    unsigned char* mB = (unsigned char*)sh_idx;
    for (int pix = tid; pix < NNODE; pix += BLOCK)
        mA[pix] = (sh_t[pix] == 0.0f) ? 1 : 0;
    __syncthreads();
    for (int it = 0; it < 5; ++it) {
        unsigned char* src = (it & 1) ? mB : mA;
        unsigned char* dst = (it & 1) ? mA : mB;
        for (int pix = tid; pix < NNODE; pix += BLOCK) {
            const int r = pix >> 5, c = pix & 31;
            unsigned char v = src[pix];
            if (r > 0)  v |= src[pix - 32];
            if (r < 31) v |= src[pix + 32];
            if (c > 0)  v |= src[pix - 1];
            if (c < 31) v |= src[pix + 1];
            dst[pix] = v;
        }
        __syncthreads();
    }
    for (int pix = tid; pix < NNODE; pix += BLOCK)
        mA[pix] = mB[pix] ^ 1;
    __syncthreads();

    for (int pix = tid; pix < NNODE; pix += BLOCK)
        sh_parent[pix] = mA[pix] ? (unsigned short)pix : (unsigned short)0xFFFF;
    __syncthreads();
    for (;;) {
        int changed = 0;
        for (int pix = tid; pix < NNODE; pix += BLOCK) {
            if (!mA[pix]) continue;
            const int r = pix >> 5, c = pix & 31;
            int m = sh_parent[pix];
            #pragma unroll
            for (int d = 0; d < 8; ++d) {
                static const int dr[8] = {-1,-1,-1, 0, 0, 1, 1, 1};
                static const int dc[8] = {-1, 0, 1,-1, 1,-1, 0, 1};
                const int rr = r + dr[d], cc = c + dc[d];
                if (rr < 0 || rr > 31 || cc < 0 || cc > 31) continue;
                const int nb = (rr << 5) + cc;
                if (mA[nb]) { int v = sh_parent[nb]; if (v < m) m = v; }
            }
            while ((int)sh_parent[m] < m) m = sh_parent[m];
            if (m < (int)sh_parent[pix]) { sh_parent[pix] = (unsigned short)m; changed = 1; }
        }
        if (!__syncthreads_or(changed)) break;
    }

    if (tid == 0) sh_L = 0;
    __syncthreads();
    for (int pix = tid; pix < NNODE; pix += BLOCK) {
        if (mA[pix] && (int)sh_parent[pix] == pix) {
            const int id = atomicAdd(&sh_L, 1);
            sh_szto[pix] = (unsigned int)(id + 1);
        }
    }
    __syncthreads();
    for (int pix = tid; pix < NNODE; pix += BLOCK) {
        unsigned char s = 0;
        if (mA[pix]) {
            int lab = (int)sh_szto[sh_parent[pix]];
            if (lab > 255) lab = 255;
            s = (unsigned char)lab;
        }
        sh_seg[pix] = s;
    }
    __syncthreads();

    const int Lraw = sh_L;
    const int mode = (Lraw <= 1) ? 0 : ((Lraw <= 4) ? 1 : 2);
    const bool skip_all = (Lraw == 0) || (Lraw == 1 && sign == 0);

    if (!skip_all) {

    if (mode == 0)      uf_init<0>(sh_parent, sh_szto, sh_cnt64, sh_seg, tid);
    else if (mode == 1) uf_init<1>(sh_parent, sh_szto, sh_cnt64, sh_seg, tid);
    else                uf_init<2>(sh_parent, sh_szto, sh_cnt64, sh_seg, tid);
    __syncthreads();

    unsigned int   K[8];
    unsigned short I[8];
    const int b8 = tid << 3;
    #pragma unroll
    for (int l = 0; l < 8; ++l) {
        const int e = b8 + l;
        if (e < NE) {
            int a, bb; edge_nodes(e, a, bb);
            float cost = sh_p[a] + sh_p[bb];
            const float g = sh_t[a] + sh_t[bb];
            if (sign == 0) { if (g > 10.0f) cost = 10.0f; }
            else           { if (g <  3.0f) cost = 0.0f;  }
            K[l] = ~__float_as_uint(cost);
            I[l] = (unsigned short)e;
        } else {
            K[l] = 0xFFFFFFFFu;
            I[l] = (unsigned short)0xFFFF;
        }
    }
    cswap(K[0],I[0],K[1],I[1], true );
    cswap(K[2],I[2],K[3],I[3], false);
    cswap(K[4],I[4],K[5],I[5], true );
    cswap(K[6],I[6],K[7],I[7], false);
    cswap(K[0],I[0],K[2],I[2], true );
    cswap(K[1],I[1],K[3],I[3], true );
    cswap(K[4],I[4],K[6],I[6], false);
    cswap(K[5],I[5],K[7],I[7], false);
    cswap(K[0],I[0],K[1],I[1], true );
    cswap(K[2],I[2],K[3],I[3], true );
    cswap(K[4],I[4],K[5],I[5], false);
    cswap(K[6],I[6],K[7],I[7], false);
    {
        const bool u8 = ((b8 & 8) == 0);
        cswap(K[0],I[0],K[4],I[4], u8); cswap(K[1],I[1],K[5],I[5], u8);
        cswap(K[2],I[2],K[6],I[6], u8); cswap(K[3],I[3],K[7],I[7], u8);
        cswap(K[0],I[0],K[2],I[2], u8); cswap(K[1],I[1],K[3],I[3], u8);
        cswap(K[4],I[4],K[6],I[6], u8); cswap(K[5],I[5],K[7],I[7], u8);
        cswap(K[0],I[0],K[1],I[1], u8); cswap(K[2],I[2],K[3],I[3], u8);
        cswap(K[4],I[4],K[5],I[5], u8); cswap(K[6],I[6],K[7],I[7], u8);
    }
    {
        uint4 k0, k1, iv;
        k0.x=K[0]; k0.y=K[1]; k0.z=K[2]; k0.w=K[3];
        k1.x=K[4]; k1.y=K[5]; k1.z=K[6]; k1.w=K[7];
        iv.x=(unsigned int)I[0] | ((unsigned int)I[1]<<16);
        iv.y=(unsigned int)I[2] | ((unsigned int)I[3]<<16);
        iv.z=(unsigned int)I[4] | ((unsigned int)I[5]<<16);
        iv.w=(unsigned int)I[6] | ((unsigned int)I[7]<<16);
        *reinterpret_cast<uint4*>(&sh_key[b8])     = k0;
        *reinterpret_cast<uint4*>(&sh_key[b8 + 4]) = k1;
        *reinterpret_cast<uint4*>(&sh_idx[b8])     = iv;
    }
    __syncthreads();

    for (int k = 16; k <= NSORT; k <<= 1) {
        for (int j = k >> 1; j >= 8; j >>= 1) {
            for (int p = tid; p < (NSORT >> 1); p += BLOCK) {
                const int i   = ((p & ~(j - 1)) << 1) | (p & (j - 1));
                const int ixj = i | j;
                const unsigned int ka = sh_key[i], kb = sh_key[ixj];
                const unsigned short ia = sh_idx[i], ib = sh_idx[ixj];
                const bool gt = (ka > kb) || (ka == kb && ia > ib);
                const bool up = ((i & k) == 0);
                if (gt == up) {
                    sh_key[i] = kb; sh_key[ixj] = ka;
                    sh_idx[i] = ib; sh_idx[ixj] = ia;
                }
            }
            __syncthreads();
        }
        {
            const uint4 k0 = *reinterpret_cast<const uint4*>(&sh_key[b8]);
            const uint4 k1 = *reinterpret_cast<const uint4*>(&sh_key[b8 + 4]);
            const uint4 iv = *reinterpret_cast<const uint4*>(&sh_idx[b8]);
            K[0]=k0.x; K[1]=k0.y; K[2]=k0.z; K[3]=k0.w;
            K[4]=k1.x; K[5]=k1.y; K[6]=k1.z; K[7]=k1.w;
            I[0]=(unsigned short)(iv.x); I[1]=(unsigned short)(iv.x>>16);
            I[2]=(unsigned short)(iv.y); I[3]=(unsigned short)(iv.y>>16);
            I[4]=(unsigned short)(iv.z); I[5]=(unsigned short)(iv.z>>16);
            I[6]=(unsigned short)(iv.w); I[7]=(unsigned short)(iv.w>>16);
            const bool u8 = ((b8 & k) == 0);
            cswap(K[0],I[0],K[4],I[4], u8); cswap(K[1],I[1],K[5],I[5], u8);
            cswap(K[2],I[2],K[6],I[6], u8); cswap(K[3],I[3],K[7],I[7], u8);
            cswap(K[0],I[0],K[2],I[2], u8); cswap(K[1],I[1],K[3],I[3], u8);
            cswap(K[4],I[4],K[6],I[6], u8); cswap(K[5],I[5],K[7],I[7], u8);
            cswap(K[0],I[0],K[1],I[1], u8); cswap(K[2],I[2],K[3],I[3], u8);
            cswap(K[4],I[4],K[5],I[5], u8); cswap(K[6],I[6],K[7],I[7], u8);
            uint4 o0, o1, ov;
            o0.x=K[0]; o0.y=K[1]; o0.z=K[2]; o0.w=K[3];
            o1.x=K[4]; o1.y=K[5]; o1.z=K[6]; o1.w=K[7];
            ov.x=(unsigned int)I[0] | ((unsigned int)I[1]<<16);
            ov.y=(unsigned int)I[2] | ((unsigned int)I[3]<<16);
            ov.z=(unsigned int)I[4] | ((unsigned int)I[5]<<16);
            ov.w=(unsigned int)I[6] | ((unsigned int)I[7]<<16);
            *reinterpret_cast<uint4*>(&sh_key[b8])     = o0;
            *reinterpret_cast<uint4*>(&sh_key[b8 + 4]) = o1;
            *reinterpret_cast<uint4*>(&sh_idx[b8])     = ov;
        }
        __syncthreads();
    }

    for (int e = tid; e < NE; e += BLOCK) sh_key[e] = 0u;
    __syncthreads();

    if (tid < 64) {
        if (mode == 0)      kruskal_run<0>(sh_parent, sh_szto, sh_cnt64, sh_key, sh_idx, sign, tid);
        else if (mode == 1) kruskal_run<1>(sh_parent, sh_szto, sh_cnt64, sh_key, sh_idx, sign, tid);
        else                kruskal_run<2>(sh_parent, sh_szto, sh_cnt64, sh_key, sh_idx, sign, tid);
    }
    __syncthreads();

    {
        float part = 0.0f;
        for (int e = tid; e < NE; e += BLOCK) part += __uint_as_float(sh_key[e]);
        for (int off = 32; off > 0; off >>= 1) part += __shfl_down(part, off, 64);
        if ((tid & 63) == 0) sh_red[tid >> 6] = (double)part;
        __syncthreads();
        if (tid == 0) sh_sn = (float)(sh_red[0] + sh_red[1] + sh_red[2] + sh_red[3]);
        __syncthreads();
    }
    const float sn = sh_sn;

    double acc = 0.0;
    for (int pix = tid; pix < NNODE; pix += BLOCK) {
        const int r = pix >> 5, c = pix & 31;
        float nw = 0.0f;
        if (c < 31) { const int e = r * 31 + c;
            float v = __uint_as_float(sh_key[e]); if (sn > 0.0f) v = v / sn;
            const float g = sh_t[pix] + sh_t[pix + 1];
            if (sign == 0) { if (g >= 3.0f) v = 0.0f; } else { if (g < 10.0f) v = 0.0f; }
            nw += v; }
        if (c > 0)  { const int e = r * 31 + c - 1;
            float v = __uint_as_float(sh_key[e]); if (sn > 0.0f) v = v / sn;
            const float g = sh_t[pix - 1] + sh_t[pix];
            if (sign == 0) { if (g >= 3.0f) v = 0.0f; } else { if (g < 10.0f) v = 0.0f; }
            nw += v; }
        if (r < 31) { const int e = NH + pix;
            float v = __uint_as_float(sh_key[e]); if (sn > 0.0f) v = v / sn;
            const float g = sh_t[pix] + sh_t[pix + 32];
            if (sign == 0) { if (g >= 3.0f) v = 0.0f; } else { if (g < 10.0f) v = 0.0f; }
            nw += v; }
        if (r > 0)  { const int e = NH + pix - 32;
            float v = __uint_as_float(sh_key[e]); if (sn > 0.0f) v = v / sn;
            const float g = sh_t[pix - 32] + sh_t[pix];
            if (sign == 0) { if (g >= 3.0f) v = 0.0f; } else { if (g < 10.0f) v = 0.0f; }
            nw += v; }
        const float p = sh_p[pix];
        float term;
        if (sign == 0) term = (p * p) * nw;
        else { const float d = 20.0f - p; term = (0.1f * (d * d)) * nw; }
        acc += (double)term;
    }
    for (int off = 32; off > 0; off >>= 1) acc += __shfl_down(acc, off, 64);
    if ((tid & 63) == 0) sh_red[tid >> 6] = acc;
    __syncthreads();
    if (tid == 0)
        atomicAdd(&acc_ws[1], sh_red[0] + sh_red[1] + sh_red[2] + sh_red[3]);

    } // !skip_all
}

__global__ __launch_bounds__(BLOCK) void mse_kernel(const float* __restrict__ pred,
                                                    const float* __restrict__ tgt,
                                                    double* __restrict__ acc_ws,
                                                    long n) {
    double acc = 0.0;
    for (long i = (long)blockIdx.x * BLOCK + threadIdx.x; i < n; i += (long)gridDim.x * BLOCK) {
        const float d = pred[i] - tgt[i];
        acc += (double)(d * d);
    }
    for (int off = 32; off > 0; off >>= 1) acc += __shfl_down(acc, off, 64);
    __shared__ double red[4];
    if ((threadIdx.x & 63) == 0) red[threadIdx.x >> 6] = acc;
    __syncthreads();
    if (threadIdx.x == 0)
        atomicAdd(&acc_ws[0], red[0] + red[1] + red[2] + red[3]);
}

__global__ void fin_kernel(const double* __restrict__ acc_ws, float* __restrict__ out, long n) {
    if (threadIdx.x == 0 && blockIdx.x == 0) {
        out[0] = (float)(acc_ws[0] / (double)n);
        out[1] = (float)(acc_ws[1] * (double)1e-4f);
    }
}

extern "C" void kernel_launch(void* const* d_in, const int* in_sizes, int n_in,
                              void* d_out, int out_size, void* d_ws, size_t ws_size,
                              hipStream_t stream) {
    const float* pred = (const float*)d_in[0];
    const float* tgt  = (const float*)d_in[1];
    float* out = (float*)d_out;
    double* acc = (double*)d_ws;

    const long n = (long)in_sizes[0];            // 4*1*128*128*128 = 8388608
    const int  B = (int)(n / 2097152);           // batches
    const int  NW = 96 * B;                      // prep work items
    const size_t need = 64 + (size_t)NW * NNODE * 9 + (size_t)NW * 4;

    hipMemsetAsync(d_ws, 0, 2 * sizeof(double), stream);
    if (ws_size >= need) {
        prep_kernel<<<NW, BLOCK, 0, stream>>>(pred, tgt, (char*)d_ws, acc, B);
        solve_kernel<<<192 * B, BLOCK, 0, stream>>>((const char*)d_ws, acc, B);
    } else {
        mse_kernel<<<1024, BLOCK, 0, stream>>>(pred, tgt, acc, n);
        conn_kernel<<<192 * B, BLOCK, 0, stream>>>(pred, tgt, acc, B);
    }
    fin_kernel<<<1, 64, 0, stream>>>(acc, out, n);
}